// Round 7
// baseline (845.660 us; speedup 1.0000x reference)
//
#include <hip/hip_runtime.h>
#include <hip/hip_bf16.h>

#define DEV static __device__ __forceinline__

#define PIX 4096
#define SEQL 4096
#define BEPS 1e-5f

DEV float b2f(unsigned short u){ unsigned int i=((unsigned int)u)<<16; float f; __builtin_memcpy(&f,&i,4); return f; }
DEV unsigned short f2b(float f){ __hip_bfloat16 h=__float2bfloat16(f); unsigned short s; __builtin_memcpy(&s,&h,2); return s; }
DEV short f2bs(float f){ return (short)f2b(f); }
DEV void unp2(unsigned int w, float&a, float&b){ unsigned int lo=w<<16, hi=w&0xffff0000u; __builtin_memcpy(&a,&lo,4); __builtin_memcpy(&b,&hi,4); }
DEV unsigned int pk2(float a,float b){ return (unsigned int)f2b(a)|((unsigned int)f2b(b)<<16); }
DEV float sigm(float x){ return 1.f/(1.f+__expf(-x)); }
DEV float silu_(float x){ return x*sigm(x); }
DEV float softplus_(float x){ return (x>20.f)?x:log1pf(__expf(x)); }

using short8 = __attribute__((ext_vector_type(8))) short;
using f32x4  = __attribute__((ext_vector_type(4))) float;
#define MFMA16 __builtin_amdgcn_mfma_f32_16x16x32_bf16

// LDS element (r,k) at r*72 + (((k>>4)^(r&3))<<4) + (k&15)   [72-short padded rows + chunk XOR]

// ============== Variant A: 128M x 128N x 64K, 4 waves 2x2, wave=64x64 (4x4 frags) ==============
#define VA_PRE() \
  const int tid=threadIdx.x, lane=tid&63, wid=tid>>6; \
  const int wm=wid&1, wn=wid>>1, fr=lane&15, fg=lane>>4; \
  const int crow=tid>>2, sch=tid&3;

#define VA_LOAD(R, P0, P1) { \
  R[0]=*(const uint4*)(P0); R[1]=*(const uint4*)((P0)+8); \
  R[2]=*(const uint4*)(P1); R[3]=*(const uint4*)((P1)+8); }

#define VA_WRITE(DST, R) { \
  int b1_=crow*72+((sch^(crow&3))*16); \
  *(uint4*)&DST[b1_]=R[0]; *(uint4*)&DST[b1_+8]=R[1]; \
  *(uint4*)&DST[b1_+64*72]=R[2]; *(uint4*)&DST[b1_+64*72+8]=R[3]; }

#define VA_STEP() \
  _Pragma("unroll") \
  for(int kk=0;kk<64;kk+=32){ \
    short8 af[4],bf[4]; const int kq_=kk+fg*8; \
    _Pragma("unroll") for(int i=0;i<4;++i){ int ml=wm*64+i*16+fr; \
      af[i]=*(const short8*)&sA[ml*72+(((kq_>>4)^(ml&3))<<4)+(kq_&15)]; } \
    _Pragma("unroll") for(int j=0;j<4;++j){ int nl=wn*64+j*16+fr; \
      bf[j]=*(const short8*)&sW[nl*72+(((kq_>>4)^(nl&3))<<4)+(kq_&15)]; } \
    _Pragma("unroll") for(int i=0;i<4;++i) \
      _Pragma("unroll") for(int j=0;j<4;++j) \
        acc[i][j]=MFMA16(af[i],bf[j],acc[i][j],0,0,0); }

// ============== Variant B: 64M x 128N x 64K, 4 waves 2x2, wave=32x64 (2x4 frags) ==============
#define VB_PRE() \
  const int tid=threadIdx.x, lane=tid&63, wid=tid>>6; \
  const int wm=wid&1, wn=wid>>1, fr=lane&15, fg=lane>>4; \
  const int crow=tid>>2, sch=tid&3; \
  const int tk=tid&63, tmb=(tid>>6)*16;

#define VB_STEP() \
  _Pragma("unroll") \
  for(int kk=0;kk<64;kk+=32){ \
    short8 af[2],bf[4]; const int kq_=kk+fg*8; \
    _Pragma("unroll") for(int i=0;i<2;++i){ int ml=wm*32+i*16+fr; \
      af[i]=*(const short8*)&sA[ml*72+(((kq_>>4)^(ml&3))<<4)+(kq_&15)]; } \
    _Pragma("unroll") for(int j=0;j<4;++j){ int nl=wn*64+j*16+fr; \
      bf[j]=*(const short8*)&sW[nl*72+(((kq_>>4)^(nl&3))<<4)+(kq_&15)]; } \
    _Pragma("unroll") for(int i=0;i<2;++i) \
      _Pragma("unroll") for(int j=0;j<4;++j) \
        acc[i][j]=MFMA16(af[i],bf[j],acc[i][j],0,0,0); }

// transpose-stage from channel-major fp32 (k1m): thread owns channel tk, 16 m at tmb
#define STAGE_A_TR_F32(EXPR16) { \
  float tv[16]; \
  _Pragma("unroll") for(int j=0;j<16;++j) tv[j]=(EXPR16); \
  _Pragma("unroll") for(int j=0;j<16;++j){ int m_=tmb+j; \
    sA[m_*72+(((tk>>4)^(m_&3))<<4)+(tk&15)]=f2bs(tv[j]); } }

// transpose-stage from channel-major bf16 (k5m)
#define STAGE_A_TR_BF16(PTR) { \
  const unsigned short* ap_=(PTR); \
  unsigned short hv[16]; \
  *(uint4*)&hv[0]=*(const uint4*)ap_; *(uint4*)&hv[8]=*(const uint4*)(ap_+8); \
  _Pragma("unroll") for(int j=0;j<16;++j){ int m_=tmb+j; \
    sA[m_*72+(((tk>>4)^(m_&3))<<4)+(tk&15)]=(short)hv[j]; } }

// ============== legacy 64x64 skeleton (k9m only) ==============
#define MF_PRE() \
  const int tid=threadIdx.x, lane=tid&63, wid=tid>>6; \
  const int wm=wid&1, wn=wid>>1, fr=lane&15, fg=lane>>4; \
  const int srow=tid>>2, sch=tid&3;

#define STAGE_A_SUM_BF(P1,P2) { \
  const unsigned short* p1_=(P1); const unsigned short* p2_=(P2); \
  unsigned short h1[16],h2[16]; \
  *(uint4*)&h1[0]=*(const uint4*)p1_; *(uint4*)&h1[8]=*(const uint4*)(p1_+8); \
  *(uint4*)&h2[0]=*(const uint4*)p2_; *(uint4*)&h2[8]=*(const uint4*)(p2_+8); \
  union { short h[16]; uint4 q[2]; } tmpa; \
  _Pragma("unroll") for(int j=0;j<16;++j) tmpa.h[j]=f2bs(b2f(h1[j])+b2f(h2[j])); \
  int base_=srow*72+((sch^(srow&3))*16); \
  *(uint4*)&sA[base_]=tmpa.q[0]; *(uint4*)&sA[base_+8]=tmpa.q[1]; }

#define STAGE_W_BF(PTR,LDK) { \
  const unsigned short* wp_=(PTR)+(size_t)(n0+srow)*(LDK)+k0+sch*16; \
  uint4 q0_=*(const uint4*)wp_, q1_=*(const uint4*)(wp_+8); \
  int sw_=((sch^(srow&3))*16); \
  *(uint4*)&sW[srow*72+sw_]=q0_; *(uint4*)&sW[srow*72+sw_+8]=q1_; }

#define MF_STEP() \
  _Pragma("unroll") \
  for(int kk=0;kk<64;kk+=32){ \
    short8 af[2],bfv[2]; const int kq_=kk+fg*8; \
    _Pragma("unroll") for(int i=0;i<2;++i){ int ml=wm*32+i*16+fr; \
      af[i]=*(const short8*)&sA[ml*72+(((kq_>>4)^(ml&3))<<4)+(kq_&15)]; } \
    _Pragma("unroll") for(int jn=0;jn<2;++jn){ int nl=wn*32+jn*16+fr; \
      bfv[jn]=*(const short8*)&sW[nl*72+(((kq_>>4)^(nl&3))<<4)+(kq_&15)]; } \
    _Pragma("unroll") for(int i=0;i<2;++i) \
      _Pragma("unroll") for(int jn=0;jn<2;++jn) \
        acc[i][jn]=MFMA16(af[i],bfv[jn],acc[i][jn],0,0,0); }

// ---------------- weight prep ----------------
__global__ __launch_bounds__(256) void kWb(const float* __restrict__ g,const float* __restrict__ ip,
  const float* __restrict__ op,const float* __restrict__ pw,const float* __restrict__ f,
  unsigned short* __restrict__ gb,unsigned short* __restrict__ ib,unsigned short* __restrict__ ob,
  unsigned short* __restrict__ pb,unsigned short* __restrict__ fb)
{
  int x=blockIdx.x*256+threadIdx.x;
  if(x<131072) gb[x]=f2b(g[x]);
  if(x<65536)  ib[x]=f2b(ip[x]);
  if(x<32768){ ob[x]=f2b(op[x]); pb[x]=f2b(pw[x]); }
  if(x<16384)  fb[x]=f2b(f[x]);
}

__global__ __launch_bounds__(256) void kWc(const float* __restrict__ dtw,const float* __restrict__ xpw,
  unsigned short* __restrict__ Wcb)
{
  int c=blockIdx.x, k=threadIdx.x;
  float a=0.f;
  #pragma unroll
  for(int i=0;i<8;++i) a+=dtw[c*8+i]*xpw[i*256+k];
  Wcb[c*256+k]=f2b(a);
}

__global__ __launch_bounds__(256) void kWse(const float* __restrict__ prw,const float* __restrict__ sse,
  unsigned short* __restrict__ Wsb)
{
  int idx=blockIdx.x*256+threadIdx.x;
  int b=idx>>17, r=idx&131071, oc=r>>10, c=r&1023;
  Wsb[idx]=f2b(prw[(size_t)oc*1024+c]*sse[b*1024+c]);
}

// ---------------- k1m: conv1x1 256->512 + BN + ReLU -> x1 bf16 [b][c][t]  (Variant B) ----------------
__global__ __launch_bounds__(256) void k1m(const float* __restrict__ FT1,const float* __restrict__ FT2,
  const unsigned short* __restrict__ Wpb,const float* __restrict__ gg,const float* __restrict__ gb,
  const float* __restrict__ gm,const float* __restrict__ gv,unsigned short* __restrict__ x1)
{
  VB_PRE();
  __shared__ __align__(16) short sA[64*72];
  __shared__ __align__(16) short sW[128*72];
  const int m0=blockIdx.x*64, n0=blockIdx.y*128, b=blockIdx.z;
  f32x4 acc[2][4]={};
  for(int k0=0;k0<256;k0+=64){
    { int c=k0+tk;
      const float* s_=(c<128)? FT1+((size_t)b*128+c)*PIX : FT2+((size_t)b*128+c-128)*PIX;
      const float* ap=s_+m0+tmb;
      STAGE_A_TR_F32(ap[j]); }
    { uint4 pw[4];
      VA_LOAD(pw, Wpb+(size_t)(n0+crow)*256+k0+sch*16, Wpb+(size_t)(n0+crow+64)*256+k0+sch*16);
      VA_WRITE(sW,pw); }
    __syncthreads();
    VB_STEP();
    __syncthreads();
  }
  #pragma unroll
  for(int jn=0;jn<4;++jn){ int oc=n0+wn*64+jn*16+fr;
    float ks=gg[oc]*rsqrtf(gv[oc]+BEPS), kb=gb[oc]-gm[oc]*ks;
    #pragma unroll
    for(int i=0;i<2;++i){ int mb=m0+wm*32+i*16+fg*4;
      float v0=fmaxf(acc[i][jn][0]*ks+kb,0.f), v1=fmaxf(acc[i][jn][1]*ks+kb,0.f);
      float v2=fmaxf(acc[i][jn][2]*ks+kb,0.f), v3=fmaxf(acc[i][jn][3]*ks+kb,0.f);
      uint2 pk; pk.x=pk2(v0,v1); pk.y=pk2(v2,v3);
      *(uint2*)&x1[((size_t)b*512+oc)*PIX+mb]=pk; } }
}

// ---------------- k2: depthwise 3x3 + BN + ReLU (bf16) ----------------
__global__ __launch_bounds__(256) void k2(const unsigned short* __restrict__ x1,const float* __restrict__ cw,
  const float* __restrict__ gg,const float* __restrict__ gb,const float* __restrict__ gm,
  const float* __restrict__ gv,unsigned short* __restrict__ x2)
{
  int gid=blockIdx.x*256+threadIdx.x;
  int wq=gid&15, h=(gid>>4)&63, bc=gid>>10;
  int c=bc&511;
  const unsigned short* src=x1+(size_t)bc*PIX;
  float wv[9];
  #pragma unroll
  for(int i=0;i<9;++i) wv[i]=cw[c*9+i];
  float ks=gg[c]*rsqrtf(gv[c]+BEPS), kb=gb[c]-gm[c]*ks;
  int wb=wq*4;
  float o[4]={};
  #pragma unroll
  for(int dh=0;dh<3;++dh){ int hh=h+dh-1; if(hh<0||hh>63) continue;
    const unsigned short* row=src+hh*64;
    float rv[6];
    #pragma unroll
    for(int j=0;j<6;++j){ int wc=wb-1+j; rv[j]=(wc>=0&&wc<64)?b2f(row[wc]):0.f; }
    #pragma unroll
    for(int dw=0;dw<3;++dw){ float wgt=wv[dh*3+dw];
      #pragma unroll
      for(int i=0;i<4;++i) o[i]+=rv[i+dw]*wgt; } }
  float v0=fmaxf(o[0]*ks+kb,0.f), v1=fmaxf(o[1]*ks+kb,0.f);
  float v2=fmaxf(o[2]*ks+kb,0.f), v3=fmaxf(o[3]*ks+kb,0.f);
  uint2 pk; pk.x=pk2(v0,v1); pk.y=pk2(v2,v3);
  *(uint2*)&x2[(size_t)bc*PIX+h*64+wb]=pk;
}

// ---------------- k3: SE mean ----------------
__global__ __launch_bounds__(256) void k3(const unsigned short* __restrict__ x1,
  const unsigned short* __restrict__ x2,float* __restrict__ sr)
{
  int bc=blockIdx.x; int cg=bc&1023, b=bc>>10;
  const unsigned short* src=(cg<512)? x1+((size_t)b*512+cg)*PIX : x2+((size_t)b*512+cg-512)*PIX;
  float s=0;
  for(int i=threadIdx.x;i<512;i+=256){
    uint4 v=((const uint4*)src)[i];
    float a0,a1; unp2(v.x,a0,a1); s+=a0+a1;
    unp2(v.y,a0,a1); s+=a0+a1;
    unp2(v.z,a0,a1); s+=a0+a1;
    unp2(v.w,a0,a1); s+=a0+a1;
  }
  #pragma unroll
  for(int off=32;off;off>>=1) s+=__shfl_down(s,off);
  __shared__ float red[4];
  if((threadIdx.x&63)==0) red[threadIdx.x>>6]=s;
  __syncthreads();
  if(threadIdx.x==0) sr[bc]=(red[0]+red[1]+red[2]+red[3])*(1.f/4096.f);
}

// ---------------- k4: SE MLP ----------------
__global__ __launch_bounds__(256) void k4(const float* __restrict__ sr,const float* __restrict__ w1,
  const float* __restrict__ w2,float* __restrict__ sOut)
{
  int b=blockIdx.x;
  __shared__ float ls[1024];
  __shared__ float pm[4][64];
  __shared__ float mid[64];
  for(int i=threadIdx.x;i<1024;i+=256) ls[i]=sr[b*1024+i];
  __syncthreads();
  int k=threadIdx.x&63, part=threadIdx.x>>6;
  float p=0;
  for(int c=part*256;c<part*256+256;++c) p+=ls[c]*w1[k*1024+c];
  pm[part][k]=p;
  __syncthreads();
  if(threadIdx.x<64) mid[threadIdx.x]=fmaxf(pm[0][threadIdx.x]+pm[1][threadIdx.x]+pm[2][threadIdx.x]+pm[3][threadIdx.x],0.f);
  __syncthreads();
  for(int j=threadIdx.x;j<1024;j+=256){
    float a=0;
    for(int kk=0;kk<64;++kk) a+=mid[kk]*w2[j*64+kk];
    sOut[b*1024+j]=sigm(a);
  }
}

// ---------------- k5m: proj 1024->128 (SE in Wsb) + BN3 -> Fp, FpT bf16 [b][t][128]  (Variant B) ----------------
__global__ __launch_bounds__(256) void k5m(const unsigned short* __restrict__ x1,
  const unsigned short* __restrict__ x2,const unsigned short* __restrict__ Wsb,
  const float* __restrict__ g3,const float* __restrict__ b3,const float* __restrict__ m3,
  const float* __restrict__ v3,unsigned short* __restrict__ Fp,unsigned short* __restrict__ FpT)
{
  VB_PRE();
  __shared__ __align__(16) short sA[64*72];
  __shared__ __align__(16) short sW[128*72];
  const int m0=blockIdx.x*64, n0=0, b=blockIdx.z;
  const unsigned short* Wb=Wsb+(size_t)b*131072;
  f32x4 acc[2][4]={};
  for(int k0=0;k0<1024;k0+=64){
    { int c=k0+tk;
      const unsigned short* s_=(c<512)? x1+((size_t)b*512+c)*PIX : x2+((size_t)b*512+c-512)*PIX;
      STAGE_A_TR_BF16(s_+m0+tmb); }
    { uint4 pw[4];
      VA_LOAD(pw, Wb+(size_t)(n0+crow)*1024+k0+sch*16, Wb+(size_t)(n0+crow+64)*1024+k0+sch*16);
      VA_WRITE(sW,pw); }
    __syncthreads();
    VB_STEP();
    __syncthreads();
  }
  #pragma unroll
  for(int jn=0;jn<4;++jn){ int oc=n0+wn*64+jn*16+fr;
    float ks=g3[oc]*rsqrtf(v3[oc]+BEPS), kb=b3[oc]-m3[oc]*ks;
    #pragma unroll
    for(int i=0;i<2;++i){ int mb=m0+wm*32+i*16+fg*4;
      #pragma unroll
      for(int p=0;p<4;++p){ int pp=mb+p; unsigned short val=f2b(acc[i][jn][p]*ks+kb);
        Fp[((size_t)b*PIX+pp)*128+oc]=val;
        int q=((pp&63)<<6)|(pp>>6);
        FpT[((size_t)b*PIX+q)*128+oc]=val; } } }
}

// ---------------- k6am: in_proj 128->512 -> xsT, zT bf16 [n][t][256]  (Variant A) ----------------
__global__ __launch_bounds__(256) void k6am(const unsigned short* __restrict__ Fp,
  const unsigned short* __restrict__ FpT,const unsigned short* __restrict__ Winb,
  unsigned short* __restrict__ xsT,unsigned short* __restrict__ zT)
{
  VA_PRE();
  __shared__ __align__(16) short sA[128*72];
  __shared__ __align__(16) short sW[128*72];
  const int m0=blockIdx.x*128, n0=blockIdx.y*128, n=blockIdx.z;
  const int d=n>>3, b=n&7;
  const unsigned short* src=((d<2)?Fp:FpT)+(size_t)b*PIX*128;
  const int rev=(d&1)?63:0;
  const int t1=m0+crow, t2=m0+crow+64;
  const size_t ro1=(size_t)((t1&~63)|((t1&63)^rev))*128;
  const size_t ro2=(size_t)((t2&~63)|((t2&63)^rev))*128;
  f32x4 acc[4][4]={};
  uint4 pa[4],pw[4];
  VA_LOAD(pa, src+ro1+sch*16, src+ro2+sch*16);
  VA_LOAD(pw, Winb+(size_t)(n0+crow)*128+sch*16, Winb+(size_t)(n0+crow+64)*128+sch*16);
  for(int k0=0;k0<128;k0+=64){
    VA_WRITE(sA,pa); VA_WRITE(sW,pw);
    __syncthreads();
    if(k0==0){
      VA_LOAD(pa, src+ro1+64+sch*16, src+ro2+64+sch*16);
      VA_LOAD(pw, Winb+(size_t)(n0+crow)*128+64+sch*16, Winb+(size_t)(n0+crow+64)*128+64+sch*16);
    }
    VA_STEP();
    __syncthreads();
  }
  #pragma unroll
  for(int jn=0;jn<4;++jn){ int r=n0+wn*64+jn*16+fr;
    unsigned short* dst; int row; bool dosilu;
    if(r<256){ dst=xsT; row=r; dosilu=false; } else { dst=zT; row=r-256; dosilu=true; }
    #pragma unroll
    for(int i=0;i<4;++i){ int mb=m0+wm*64+i*16+fg*4;
      #pragma unroll
      for(int p=0;p<4;++p){ float v=acc[i][jn][p]; if(dosilu) v=silu_(v);
        dst[((size_t)n*SEQL+mb+p)*256+row]=f2b(v); } } }
}

// ---------------- k6b: causal conv1d (k=4) + SiLU (token-major) ----------------
__global__ __launch_bounds__(256) void k6b(const unsigned short* __restrict__ xsT,
  const float* __restrict__ cw,const float* __restrict__ cb,unsigned short* __restrict__ uT)
{
  int gid=blockIdx.x*256+threadIdx.x;
  int cb8=gid&31, tb=(gid>>5)&511, n=gid>>14;
  int c0=cb8*8, t0=tb*8;
  const unsigned short* base=xsT+(size_t)n*SEQL*256+c0;
  float w0[8],w1[8],w2[8],w3[8],bb[8];
  #pragma unroll
  for(int j=0;j<8;++j){ float4 wv=*(const float4*)&cw[(c0+j)*4];
    w0[j]=wv.x; w1[j]=wv.y; w2[j]=wv.z; w3[j]=wv.w; bb[j]=cb[c0+j]; }
  float ra[8],rb[8],rc[8],rd[8];
  #pragma unroll
  for(int j=0;j<8;++j){ ra[j]=0.f; rb[j]=0.f; rc[j]=0.f; }
  if(t0>=3){
    uint4 v;
    v=*(const uint4*)(base+(size_t)(t0-3)*256); unp2(v.x,ra[0],ra[1]);unp2(v.y,ra[2],ra[3]);unp2(v.z,ra[4],ra[5]);unp2(v.w,ra[6],ra[7]);
    v=*(const uint4*)(base+(size_t)(t0-2)*256); unp2(v.x,rb[0],rb[1]);unp2(v.y,rb[2],rb[3]);unp2(v.z,rb[4],rb[5]);unp2(v.w,rb[6],rb[7]);
    v=*(const uint4*)(base+(size_t)(t0-1)*256); unp2(v.x,rc[0],rc[1]);unp2(v.y,rc[2],rc[3]);unp2(v.z,rc[4],rc[5]);unp2(v.w,rc[6],rc[7]);
  }
  unsigned short* ob=uT+(size_t)n*SEQL*256+c0;
  for(int j=0;j<8;++j){
    uint4 v=*(const uint4*)(base+(size_t)(t0+j)*256);
    unp2(v.x,rd[0],rd[1]);unp2(v.y,rd[2],rd[3]);unp2(v.z,rd[4],rd[5]);unp2(v.w,rd[6],rd[7]);
    float o[8];
    #pragma unroll
    for(int q=0;q<8;++q){
      o[q]=silu_(ra[q]*w0[q]+rb[q]*w1[q]+rc[q]*w2[q]+rd[q]*w3[q]+bb[q]);
      ra[q]=rb[q]; rb[q]=rc[q]; rc[q]=rd[q];
    }
    uint4 ov; ov.x=pk2(o[0],o[1]); ov.y=pk2(o[2],o[3]); ov.z=pk2(o[4],o[5]); ov.w=pk2(o[6],o[7]);
    *(uint4*)(ob+(size_t)(t0+j)*256)=ov;
  }
}

// ---------------- k6cm: dt GEMM + softplus -> dtT bf16 [n][t][256]  (Variant A) ----------------
__global__ __launch_bounds__(256) void k6cm(const unsigned short* __restrict__ uT,
  const unsigned short* __restrict__ Wcb,const float* __restrict__ dtb,
  unsigned short* __restrict__ dtT)
{
  VA_PRE();
  __shared__ __align__(16) short sA[128*72];
  __shared__ __align__(16) short sW[128*72];
  const int m0=blockIdx.x*128, n0=blockIdx.y*128, n=blockIdx.z;
  const unsigned short* u1=uT+(size_t)n*SEQL*256+(size_t)(m0+crow)*256;
  const unsigned short* u2=u1+(size_t)64*256;
  f32x4 acc[4][4]={};
  uint4 pa[4],pw[4];
  VA_LOAD(pa, u1+sch*16, u2+sch*16);
  VA_LOAD(pw, Wcb+(size_t)(n0+crow)*256+sch*16, Wcb+(size_t)(n0+crow+64)*256+sch*16);
  for(int k0=0;k0<256;k0+=64){
    VA_WRITE(sA,pa); VA_WRITE(sW,pw);
    __syncthreads();
    if(k0<192){
      VA_LOAD(pa, u1+k0+64+sch*16, u2+k0+64+sch*16);
      VA_LOAD(pw, Wcb+(size_t)(n0+crow)*256+k0+64+sch*16, Wcb+(size_t)(n0+crow+64)*256+k0+64+sch*16);
    }
    VA_STEP();
    __syncthreads();
  }
  #pragma unroll
  for(int jn=0;jn<4;++jn){ int oc=n0+wn*64+jn*16+fr;
    float bias=dtb[oc];
    #pragma unroll
    for(int i=0;i<4;++i){ int mb=m0+wm*64+i*16+fg*4;
      #pragma unroll
      for(int p=0;p<4;++p)
        dtT[((size_t)n*SEQL+mb+p)*256+oc]=f2b(softplus_(acc[i][jn][p]+bias)); } }
}

// ---------------- k6bc: Bc/Cc = u @ xpw[8:10].T (wave per token) ----------------
__global__ __launch_bounds__(256) void k6bc(const unsigned short* __restrict__ uT,
  const float* __restrict__ xpw,float* __restrict__ Bc,float* __restrict__ Cc)
{
  int inst=blockIdx.x*4+(threadIdx.x>>6);
  int ln=threadIdx.x&63;
  int n=inst>>12, t=inst&4095;
  const unsigned short* up=uT+((size_t)n*SEQL+t)*256+ln*4;
  uint2 uu=*(const uint2*)up;
  float u0,u1,u2,u3; unp2(uu.x,u0,u1); unp2(uu.y,u2,u3);
  float4 w8=*(const float4*)&xpw[8*256+ln*4];
  float4 w9=*(const float4*)&xpw[9*256+ln*4];
  float sb=u0*w8.x+u1*w8.y+u2*w8.z+u3*w8.w;
  float sc=u0*w9.x+u1*w9.y+u2*w9.z+u3*w9.w;
  #pragma unroll
  for(int off=32;off;off>>=1){ sb+=__shfl_xor(sb,off); sc+=__shfl_xor(sc,off); }
  if(ln==0){ Bc[(size_t)n*SEQL+t]=sb; Cc[(size_t)n*SEQL+t]=sc; }
}

// ---------------- k7: chunked scan, 32 chunks of 128, 4 channels/lane ----------------
__global__ __launch_bounds__(256) void k7p1(const unsigned short* __restrict__ uT,
  const unsigned short* __restrict__ dtT,const float* __restrict__ Bc,
  const float* __restrict__ A_log,float* __restrict__ Pq)
{
  int g=blockIdx.x*256+threadIdx.x;
  int cq=g&63, ch=(g>>6)&31, n=g>>11;
  int c0=cq*4;
  float A0=-__expf(A_log[c0]),A1=-__expf(A_log[c0+1]),A2=-__expf(A_log[c0+2]),A3=-__expf(A_log[c0+3]);
  size_t tbase=((size_t)n*SEQL+ch*128)*256+c0;
  const float* bp=Bc+(size_t)n*SEQL+ch*128;
  float P0=1,P1=1,P2=1,P3=1,q0=0,q1=0,q2=0,q3=0;
  for(int t=0;t<128;++t){
    uint2 uu=*(const uint2*)&uT[tbase+(size_t)t*256];
    uint2 dd=*(const uint2*)&dtT[tbase+(size_t)t*256];
    float u0,u1,u2,u3,d0,d1,d2,d3;
    unp2(uu.x,u0,u1); unp2(uu.y,u2,u3);
    unp2(dd.x,d0,d1); unp2(dd.y,d2,d3);
    float bv=bp[t];
    float e0=__expf(d0*A0),e1=__expf(d1*A1),e2=__expf(d2*A2),e3=__expf(d3*A3);
    q0=q0*e0+d0*bv*u0; q1=q1*e1+d1*bv*u1; q2=q2*e2+d2*bv*u2; q3=q3*e3+d3*bv*u3;
    P0*=e0; P1*=e1; P2*=e2; P3*=e3;
  }
  size_t o=(((size_t)n*256+c0)*32+ch)*2;
  Pq[o]=P0; Pq[o+1]=q0; Pq[o+64]=P1; Pq[o+65]=q1;
  Pq[o+128]=P2; Pq[o+129]=q2; Pq[o+192]=P3; Pq[o+193]=q3;
}

__global__ __launch_bounds__(256) void k7mid(const float* __restrict__ Pq,float* __restrict__ h0)
{
  int nc=blockIdx.x*256+threadIdx.x;
  float h=0.f;
  for(int ch=0;ch<32;++ch){
    h0[(size_t)nc*32+ch]=h;
    h=h*Pq[((size_t)nc*32+ch)*2]+Pq[((size_t)nc*32+ch)*2+1];
  }
}

__global__ __launch_bounds__(256) void k7p2(unsigned short* __restrict__ uT,
  const unsigned short* __restrict__ dtT,const unsigned short* __restrict__ zT,
  const float* __restrict__ Bc,const float* __restrict__ Cc,
  const float* __restrict__ A_log,const float* __restrict__ Dp,
  const float* __restrict__ h0)
{
  int g=blockIdx.x*256+threadIdx.x;
  int cq=g&63, ch=(g>>6)&31, n=g>>11;
  int c0=cq*4;
  float A0=-__expf(A_log[c0]),A1=-__expf(A_log[c0+1]),A2=-__expf(A_log[c0+2]),A3=-__expf(A_log[c0+3]);
  float D0=Dp[c0],D1=Dp[c0+1],D2=Dp[c0+2],D3=Dp[c0+3];
  size_t tbase=((size_t)n*SEQL+ch*128)*256+c0;
  const float* bp=Bc+(size_t)n*SEQL+ch*128;
  const float* cp=Cc+(size_t)n*SEQL+ch*128;
  size_t hb=((size_t)n*256+c0)*32+ch;
  float h0v=h0[hb],h1v=h0[hb+32],h2v=h0[hb+64],h3v=h0[hb+96];
  for(int t=0;t<128;++t){
    uint2 uu=*(const uint2*)&uT[tbase+(size_t)t*256];
    uint2 dd=*(const uint2*)&dtT[tbase+(size_t)t*256];
    uint2 zz=*(const uint2*)&zT[tbase+(size_t)t*256];
    float u0,u1,u2,u3,d0,d1,d2,d3,z0,z1,z2,z3;
    unp2(uu.x,u0,u1); unp2(uu.y,u2,u3);
    unp2(dd.x,d0,d1); unp2(dd.y,d2,d3);
    unp2(zz.x,z0,z1); unp2(zz.y,z2,z3);
    float bv=bp[t], cv=cp[t];
    float e0=__expf(d0*A0),e1=__expf(d1*A1),e2=__expf(d2*A2),e3=__expf(d3*A3);
    h0v=h0v*e0+d0*bv*u0; h1v=h1v*e1+d1*bv*u1; h2v=h2v*e2+d2*bv*u2; h3v=h3v*e3+d3*bv*u3;
    float y0=(h0v*cv+u0*D0)*z0, y1=(h1v*cv+u1*D1)*z1;
    float y2=(h2v*cv+u2*D2)*z2, y3=(h3v*cv+u3*D3)*z3;
    uint2 oo; oo.x=pk2(y0,y1); oo.y=pk2(y2,y3);
    *(uint2*)&uT[tbase+(size_t)t*256]=oo;
  }
}

// ---------------- k8am: out_proj 256->128 -> Y4 bf16 [n][t][128]  (Variant A) ----------------
__global__ __launch_bounds__(256) void k8am(const unsigned short* __restrict__ yT,
  const unsigned short* __restrict__ Woutb,unsigned short* __restrict__ Y4)
{
  VA_PRE();
  __shared__ __align__(16) short sA[128*72];
  __shared__ __align__(16) short sW[128*72];
  const int m0=blockIdx.x*128, n0=0, n=blockIdx.z;
  const unsigned short* u1=yT+(size_t)n*SEQL*256+(size_t)(m0+crow)*256;
  const unsigned short* u2=u1+(size_t)64*256;
  f32x4 acc[4][4]={};
  uint4 pa[4],pw[4];
  VA_LOAD(pa, u1+sch*16, u2+sch*16);
  VA_LOAD(pw, Woutb+(size_t)(n0+crow)*256+sch*16, Woutb+(size_t)(n0+crow+64)*256+sch*16);
  for(int k0=0;k0<256;k0+=64){
    VA_WRITE(sA,pa); VA_WRITE(sW,pw);
    __syncthreads();
    if(k0<192){
      VA_LOAD(pa, u1+k0+64+sch*16, u2+k0+64+sch*16);
      VA_LOAD(pw, Woutb+(size_t)(n0+crow)*256+k0+64+sch*16, Woutb+(size_t)(n0+crow+64)*256+k0+64+sch*16);
    }
    VA_STEP();
    __syncthreads();
  }
  #pragma unroll
  for(int jn=0;jn<4;++jn){ int oc=n0+wn*64+jn*16+fr;
    #pragma unroll
    for(int i=0;i<4;++i){ int mb=m0+wm*64+i*16+fg*4;
      #pragma unroll
      for(int p=0;p<4;++p)
        Y4[((size_t)n*SEQL+mb+p)*128+oc]=f2b(acc[i][jn][p]); } }
}

// ---------------- k8bm: pi GEMM + gate + 4-dir sum -> ysum bf16 [b][t][128]  (Variant A) ----------------
DEV const unsigned short* k8b_aptr(const unsigned short* src,const unsigned short* Y4n,
  int m0,int r,int rev,int k0p,int sch)
{
  if(k0p<128){ int t=m0+r; int tm=(t&~63)|((t&63)^rev);
    return src+(size_t)tm*128+k0p+sch*16; }
  return Y4n+(size_t)(m0+r)*128+(k0p-128)+sch*16;
}

__global__ __launch_bounds__(256) void k8bm(const unsigned short* __restrict__ Fp,
  const unsigned short* __restrict__ FpT,const unsigned short* __restrict__ Y4,
  const unsigned short* __restrict__ piwb,const float* __restrict__ pib,
  unsigned short* __restrict__ ysum)
{
  VA_PRE();
  __shared__ __align__(16) short sA[128*72];
  __shared__ __align__(16) short sW[128*72];
  const int m0=blockIdx.x*128, n0=0, b=blockIdx.z;
  f32x4 gs[4][4]={};
  for(int d=0;d<4;++d){
    const int n=d*8+b;
    const unsigned short* src=((d<2)?Fp:FpT)+(size_t)b*PIX*128;
    const unsigned short* Y4n=Y4+(size_t)n*SEQL*128;
    const int rev=(d&1)?63:0;
    f32x4 acc[4][4]={};
    uint4 pa[4],pw[4];
    VA_LOAD(pa, k8b_aptr(src,Y4n,m0,crow,rev,0,sch), k8b_aptr(src,Y4n,m0,crow+64,rev,0,sch));
    VA_LOAD(pw, piwb+(size_t)(n0+crow)*256+sch*16, piwb+(size_t)(n0+crow+64)*256+sch*16);
    for(int k0=0;k0<256;k0+=64){
      VA_WRITE(sA,pa); VA_WRITE(sW,pw);
      __syncthreads();
      if(k0<192){
        VA_LOAD(pa, k8b_aptr(src,Y4n,m0,crow,rev,k0+64,sch), k8b_aptr(src,Y4n,m0,crow+64,rev,k0+64,sch));
        VA_LOAD(pw, piwb+(size_t)(n0+crow)*256+k0+64+sch*16, piwb+(size_t)(n0+crow+64)*256+k0+64+sch*16);
      }
      VA_STEP();
      __syncthreads();
    }
    #pragma unroll
    for(int i=0;i<4;++i){
      #pragma unroll
      for(int jn=0;jn<4;++jn){
        int oc=n0+wn*64+jn*16+fr;
        int mb=m0+wm*64+i*16+fg*4;
        float pb=pib[oc];
        #pragma unroll
        for(int p=0;p<4;++p){
          int t=mb+p; int tm=(t&~63)|((t&63)^rev);
          float pi=sigm(acc[i][jn][p]+pb);
          float x4=b2f(src[(size_t)tm*128+oc]);
          float y4=b2f(Y4n[(size_t)t*128+oc]);
          gs[i][jn][p]+=y4*pi+x4*(1.f-pi);
        }
      }
    }
  }
  #pragma unroll
  for(int i=0;i<4;++i)
    #pragma unroll
    for(int jn=0;jn<4;++jn){
      int oc=n0+wn*64+jn*16+fr;
      int mb=m0+wm*64+i*16+fg*4;
      #pragma unroll
      for(int p=0;p<4;++p)
        ysum[((size_t)b*PIX+mb+p)*128+oc]=f2b(gs[i][jn][p]);
    }
}

// ---------------- k9m: final conv1x1 ((ysum+Fp) @ fw) -> out fp32 [b][c][t]  (legacy 64x64) ----------------
__global__ __launch_bounds__(256) void k9m(const unsigned short* __restrict__ ysum,
  const unsigned short* __restrict__ Fp,const unsigned short* __restrict__ fwb,
  float* __restrict__ out)
{
  MF_PRE();
  __shared__ __align__(16) short sA[64*72];
  __shared__ __align__(16) short sW[64*72];
  const int m0=blockIdx.x*64, n0=blockIdx.y*64, b=blockIdx.z;
  f32x4 acc[2][2]={};
  for(int k0=0;k0<128;k0+=64){
    { size_t off=((size_t)b*PIX+m0+srow)*128+k0+sch*16;
      STAGE_A_SUM_BF(ysum+off,Fp+off); }
    STAGE_W_BF(fwb,128);
    __syncthreads();
    MF_STEP();
    __syncthreads();
  }
  #pragma unroll
  for(int jn=0;jn<2;++jn){ int oc=n0+wn*32+jn*16+fr;
    #pragma unroll
    for(int i=0;i<2;++i){ int mb=m0+wm*32+i*16+fg*4;
      *(float4*)&out[((size_t)b*128+oc)*PIX+mb]=
        make_float4(acc[i][jn][0],acc[i][jn][1],acc[i][jn][2],acc[i][jn][3]); } }
}

extern "C" void kernel_launch(void* const* d_in,const int* in_sizes,int n_in,
  void* d_out,int out_size,void* d_ws,size_t ws_size,hipStream_t stream)
{
  (void)in_sizes; (void)n_in; (void)out_size; (void)ws_size;
  const float* FT1=(const float*)d_in[0];
  const float* FT2=(const float*)d_in[1];
  const float* gpw=(const float*)d_in[2];
  const float* g1g=(const float*)d_in[3];
  const float* g1b=(const float*)d_in[4];
  const float* g1m=(const float*)d_in[5];
  const float* g1v=(const float*)d_in[6];
  const float* gcw=(const float*)d_in[7];
  const float* g2g=(const float*)d_in[8];
  const float* g2b=(const float*)d_in[9];
  const float* g2m=(const float*)d_in[10];
  const float* g2v=(const float*)d_in[11];
  const float* sw1=(const float*)d_in[12];
  const float* sw2=(const float*)d_in[13];
  const float* prw=(const float*)d_in[14];
  const float* b3g=(const float*)d_in[15];
  const float* b3b=(const float*)d_in[16];
  const float* b3m=(const float*)d_in[17];
  const float* b3v=(const float*)d_in[18];
  const float* ipw=(const float*)d_in[19];
  const float* c1w=(const float*)d_in[20];
  const float* c1b=(const float*)d_in[21];
  const float* xpw=(const float*)d_in[22];
  const float* dtw=(const float*)d_in[23];
  const float* dtb=(const float*)d_in[24];
  const float* Alog=(const float*)d_in[25];
  const float* Dp=(const float*)d_in[26];
  const float* opw=(const float*)d_in[27];
  const float* piw=(const float*)d_in[28];
  const float* pib=(const float*)d_in[29];
  const float* fw=(const float*)d_in[30];

  char* w=(char*)d_ws;
  const size_t MB=1ull<<20;
  unsigned short* x1b =(unsigned short*)(w);            // 32MB bf16 [b][c][t]
  unsigned short* x2b =(unsigned short*)(w+32*MB);      // 32MB
  unsigned short* uT  =(unsigned short*)(w);            // 64MB [n][t][256] (after k5m)
  unsigned short* xsT =(unsigned short*)(w+64*MB);      // 64MB [n][t][256]
  unsigned short* dtT =(unsigned short*)(w+64*MB);      // 64MB (after k6b)
  unsigned short* Y4  =(unsigned short*)(w+64*MB);      // 32MB (after k7p2)
  unsigned short* zT  =(unsigned short*)(w+128*MB);     // 64MB [n][t][256]
  unsigned short* Fpb =(unsigned short*)(w+192*MB);     // 8MB  [b][t][128]
  unsigned short* FpTb=(unsigned short*)(w+200*MB);     // 8MB
  unsigned short* ysb =(unsigned short*)(w+208*MB);     // 8MB
  float* Bc =(float*)(w+216*MB);                        // 512KB
  float* Cc =(float*)(w+216*MB+512*1024);               // 512KB
  float* sr =(float*)(w+217*MB);                        // 32KB
  float* sse=(float*)(w+217*MB+32*1024);                // 32KB
  float* Pq =(float*)(w+218*MB);                        // 2MB
  float* h0 =(float*)(w+220*MB);                        // 1MB
  unsigned short* Wcb =(unsigned short*)(w+221*MB);     // 128KB
  unsigned short* gpwb=(unsigned short*)(w+222*MB);     // 256KB
  unsigned short* ipwb=(unsigned short*)(w+223*MB);     // 128KB
  unsigned short* opwb=(unsigned short*)(w+224*MB);     // 64KB
  unsigned short* piwb=(unsigned short*)(w+224*MB+64*1024); // 64KB
  unsigned short* fwb =(unsigned short*)(w+224*MB+128*1024);// 32KB
  unsigned short* Wsb =(unsigned short*)(w+225*MB);     // 2MB

  kWb<<<512,256,0,stream>>>(gpw,ipw,opw,piw,fw,gpwb,ipwb,opwb,piwb,fwb);
  kWc<<<256,256,0,stream>>>(dtw,xpw,Wcb);
  k1m<<<dim3(64,4,8),256,0,stream>>>(FT1,FT2,gpwb,g1g,g1b,g1m,g1v,x1b);
  k2<<<16384,256,0,stream>>>(x1b,gcw,g2g,g2b,g2m,g2v,x2b);
  k3<<<8192,256,0,stream>>>(x1b,x2b,sr);
  k4<<<8,256,0,stream>>>(sr,sw1,sw2,sse);
  kWse<<<4096,256,0,stream>>>(prw,sse,Wsb);
  k5m<<<dim3(64,1,8),256,0,stream>>>(x1b,x2b,Wsb,b3g,b3b,b3m,b3v,Fpb,FpTb);
  k6am<<<dim3(32,4,32),256,0,stream>>>(Fpb,FpTb,ipwb,xsT,zT);
  k6b<<<2048,256,0,stream>>>(xsT,c1w,c1b,uT);
  k6cm<<<dim3(32,2,32),256,0,stream>>>(uT,Wcb,dtb,dtT);
  k6bc<<<32768,256,0,stream>>>(uT,xpw,Bc,Cc);
  k7p1<<<256,256,0,stream>>>(uT,dtT,Bc,Alog,Pq);
  k7mid<<<32,256,0,stream>>>(Pq,h0);
  k7p2<<<256,256,0,stream>>>(uT,dtT,zT,Bc,Cc,Alog,Dp,h0);
  k8am<<<dim3(32,1,32),256,0,stream>>>(uT,opwb,Y4);
  k8bm<<<dim3(32,1,8),256,0,stream>>>(Fpb,FpTb,Y4,piwb,pib,ysb);
  k9m<<<dim3(64,2,8),256,0,stream>>>(ysb,Fpb,fwb,(float*)d_out);
}

// Round 8
// 593.575 us; speedup vs baseline: 1.4247x; 1.4247x over previous
//
#include <hip/hip_runtime.h>
#include <hip/hip_bf16.h>

#define DEV static __device__ __forceinline__

#define PIX 4096
#define SEQL 4096
#define BEPS 1e-5f

DEV float b2f(unsigned short u){ unsigned int i=((unsigned int)u)<<16; float f; __builtin_memcpy(&f,&i,4); return f; }
DEV unsigned short f2b(float f){ __hip_bfloat16 h=__float2bfloat16(f); unsigned short s; __builtin_memcpy(&s,&h,2); return s; }
DEV short f2bs(float f){ return (short)f2b(f); }
DEV void unp2(unsigned int w, float&a, float&b){ unsigned int lo=w<<16, hi=w&0xffff0000u; __builtin_memcpy(&a,&lo,4); __builtin_memcpy(&b,&hi,4); }
DEV unsigned int pk2(float a,float b){ return (unsigned int)f2b(a)|((unsigned int)f2b(b)<<16); }
DEV float sigm(float x){ return 1.f/(1.f+__expf(-x)); }
DEV float silu_(float x){ return x*sigm(x); }
DEV float softplus_(float x){ return (x>15.f)?x:__logf(1.f+__expf(x)); }

using short8 = __attribute__((ext_vector_type(8))) short;
using f32x4  = __attribute__((ext_vector_type(4))) float;
#define MFMA16 __builtin_amdgcn_mfma_f32_16x16x32_bf16

// ================= MFMA GEMM skeleton =================
// tile 64(M) x 64(N) x 64(K), 256 threads = 4 waves (2x2), 2x2 16x16x32 frags/wave.
// sA/sW: [row][k] (72 shorts/row), chunk-XOR swizzle:
//   element (r,k) at r*72 + (((k>>4)^(r&3))<<4) + (k&15)
// All MFMA operand reads are ds_read_b128.
// D-layout invariant (verified R3/R4): D rows (fg*4+reg) index the FIRST operand's
// row-range; D cols (fr) index the SECOND operand's row-range.

#define MF_PRE() \
  const int tid=threadIdx.x; \
  const int lane=tid&63, wid=tid>>6; \
  const int wm=wid&1, wn=wid>>1; \
  const int fr=lane&15, fg=lane>>4; \
  const int srow=tid>>2, sch=tid&3; \
  const int tk=tid&63, tmb=(tid>>6)*16;

#define STAGE_A_TOK_BF(PTR) { \
  const unsigned short* ap_=(PTR); \
  uint4 q0_=*(const uint4*)ap_, q1_=*(const uint4*)(ap_+8); \
  int base_=srow*72+((sch^(srow&3))*16); \
  *(uint4*)&sA[base_]=q0_; *(uint4*)&sA[base_+8]=q1_; }

#define STAGE_A_SUM_BF(P1,P2) { \
  const unsigned short* p1_=(P1); const unsigned short* p2_=(P2); \
  unsigned short h1[16],h2[16]; \
  *(uint4*)&h1[0]=*(const uint4*)p1_; *(uint4*)&h1[8]=*(const uint4*)(p1_+8); \
  *(uint4*)&h2[0]=*(const uint4*)p2_; *(uint4*)&h2[8]=*(const uint4*)(p2_+8); \
  union { short h[16]; uint4 q[2]; } tmpa; \
  _Pragma("unroll") for(int j=0;j<16;++j) tmpa.h[j]=f2bs(b2f(h1[j])+b2f(h2[j])); \
  int base_=srow*72+((sch^(srow&3))*16); \
  *(uint4*)&sA[base_]=tmpa.q[0]; *(uint4*)&sA[base_+8]=tmpa.q[1]; }

#define STAGE_A_TR_F32(EXPR16) { \
  float tv[16]; \
  _Pragma("unroll") for(int j=0;j<16;++j) tv[j]=(EXPR16); \
  _Pragma("unroll") for(int j=0;j<16;++j){ int m_=tmb+j; \
    sA[m_*72+(((tk>>4)^(m_&3))<<4)+(tk&15)]=f2bs(tv[j]); } }

#define STAGE_A_TR_BF16(PTR) { \
  const unsigned short* ap_=(PTR); \
  unsigned short hv[16]; \
  *(uint4*)&hv[0]=*(const uint4*)ap_; *(uint4*)&hv[8]=*(const uint4*)(ap_+8); \
  _Pragma("unroll") for(int j=0;j<16;++j){ int m_=tmb+j; \
    sA[m_*72+(((tk>>4)^(m_&3))<<4)+(tk&15)]=(short)hv[j]; } }

#define STAGE_W_BF(PTR,LDK) { \
  const unsigned short* wp_=(PTR)+(size_t)(n0+srow)*(LDK)+k0+sch*16; \
  uint4 q0_=*(const uint4*)wp_, q1_=*(const uint4*)(wp_+8); \
  int sw_=((sch^(srow&3))*16); \
  *(uint4*)&sW[srow*72+sw_]=q0_; *(uint4*)&sW[srow*72+sw_+8]=q1_; }

// normal: first operand = sA (tokens/pixels), D rows = M
#define MF_STEP() \
  _Pragma("unroll") \
  for(int kk=0;kk<64;kk+=32){ \
    short8 af[2],bfv[2]; const int kq_=kk+fg*8; \
    _Pragma("unroll") for(int i=0;i<2;++i){ int ml=wm*32+i*16+fr; \
      af[i]=*(const short8*)&sA[ml*72+(((kq_>>4)^(ml&3))<<4)+(kq_&15)]; } \
    _Pragma("unroll") for(int jn=0;jn<2;++jn){ int nl=wn*32+jn*16+fr; \
      bfv[jn]=*(const short8*)&sW[nl*72+(((kq_>>4)^(nl&3))<<4)+(kq_&15)]; } \
    _Pragma("unroll") for(int i=0;i<2;++i) \
      _Pragma("unroll") for(int jn=0;jn<2;++jn) \
        acc[i][jn]=MFMA16(af[i],bfv[jn],acc[i][jn],0,0,0); }

// swapped: first operand = sW (channels), D rows = channels -> lane holds 4 consecutive
// channels at one token => uint2 epilogue stores. acc[i][j]: i=channel frag, j=token frag.
#define MF_STEP_SW() \
  _Pragma("unroll") \
  for(int kk=0;kk<64;kk+=32){ \
    short8 tf[2],wf[2]; const int kq_=kk+fg*8; \
    _Pragma("unroll") for(int j=0;j<2;++j){ int ml=wm*32+j*16+fr; \
      tf[j]=*(const short8*)&sA[ml*72+(((kq_>>4)^(ml&3))<<4)+(kq_&15)]; } \
    _Pragma("unroll") for(int i=0;i<2;++i){ int nl=wn*32+i*16+fr; \
      wf[i]=*(const short8*)&sW[nl*72+(((kq_>>4)^(nl&3))<<4)+(kq_&15)]; } \
    _Pragma("unroll") for(int i=0;i<2;++i) \
      _Pragma("unroll") for(int j=0;j<2;++j) \
        acc[i][j]=MFMA16(wf[i],tf[j],acc[i][j],0,0,0); }

// ---------------- weight prep ----------------
__global__ __launch_bounds__(256) void kWb(const float* __restrict__ g,const float* __restrict__ ip,
  const float* __restrict__ op,const float* __restrict__ pw,const float* __restrict__ f,
  unsigned short* __restrict__ gb,unsigned short* __restrict__ ib,unsigned short* __restrict__ ob,
  unsigned short* __restrict__ pb,unsigned short* __restrict__ fb)
{
  int x=blockIdx.x*256+threadIdx.x;
  if(x<131072) gb[x]=f2b(g[x]);
  if(x<65536)  ib[x]=f2b(ip[x]);
  if(x<32768){ ob[x]=f2b(op[x]); pb[x]=f2b(pw[x]); }
  if(x<16384)  fb[x]=f2b(f[x]);
}

__global__ __launch_bounds__(256) void kWc(const float* __restrict__ dtw,const float* __restrict__ xpw,
  unsigned short* __restrict__ Wcb)
{
  int c=blockIdx.x, k=threadIdx.x;
  float a=0.f;
  #pragma unroll
  for(int i=0;i<8;++i) a+=dtw[c*8+i]*xpw[i*256+k];
  Wcb[c*256+k]=f2b(a);
}

__global__ __launch_bounds__(256) void kWse(const float* __restrict__ prw,const float* __restrict__ sse,
  unsigned short* __restrict__ Wsb)
{
  int idx=blockIdx.x*256+threadIdx.x;
  int b=idx>>17, r=idx&131071, oc=r>>10, c=r&1023;
  Wsb[idx]=f2b(prw[(size_t)oc*1024+c]*sse[b*1024+c]);
}

// ---------------- k1m: conv1x1 256->512 + BN + ReLU -> x1 bf16 [b][c][t] ----------------
__global__ __launch_bounds__(256) void k1m(const float* __restrict__ FT1,const float* __restrict__ FT2,
  const unsigned short* __restrict__ Wpb,const float* __restrict__ gg,const float* __restrict__ gb,
  const float* __restrict__ gm,const float* __restrict__ gv,unsigned short* __restrict__ x1)
{
  MF_PRE();
  __shared__ __align__(16) short sA[64*72];
  __shared__ __align__(16) short sW[64*72];
  const int m0=blockIdx.x*64, n0=blockIdx.y*64, b=blockIdx.z;
  f32x4 acc[2][2]={};
  for(int k0=0;k0<256;k0+=64){
    { int c=k0+tk;
      const float* s_=(c<128)? FT1+((size_t)b*128+c)*PIX : FT2+((size_t)b*128+c-128)*PIX;
      const float* ap=s_+m0+tmb;
      STAGE_A_TR_F32(ap[j]); }
    STAGE_W_BF(Wpb,256);
    __syncthreads();
    MF_STEP();
    __syncthreads();
  }
  #pragma unroll
  for(int jn=0;jn<2;++jn){ int oc=n0+wn*32+jn*16+fr;
    float ks=gg[oc]*rsqrtf(gv[oc]+BEPS), kb=gb[oc]-gm[oc]*ks;
    #pragma unroll
    for(int i=0;i<2;++i){ int mb=m0+wm*32+i*16+fg*4;
      float v0=fmaxf(acc[i][jn][0]*ks+kb,0.f), v1=fmaxf(acc[i][jn][1]*ks+kb,0.f);
      float v2=fmaxf(acc[i][jn][2]*ks+kb,0.f), v3=fmaxf(acc[i][jn][3]*ks+kb,0.f);
      uint2 pk; pk.x=pk2(v0,v1); pk.y=pk2(v2,v3);
      *(uint2*)&x1[((size_t)b*512+oc)*PIX+mb]=pk; } }
}

// ---------------- k2: depthwise 3x3 + BN + ReLU (bf16) ----------------
__global__ __launch_bounds__(256) void k2(const unsigned short* __restrict__ x1,const float* __restrict__ cw,
  const float* __restrict__ gg,const float* __restrict__ gb,const float* __restrict__ gm,
  const float* __restrict__ gv,unsigned short* __restrict__ x2)
{
  int gid=blockIdx.x*256+threadIdx.x;
  int wq=gid&15, h=(gid>>4)&63, bc=gid>>10;
  int c=bc&511;
  const unsigned short* src=x1+(size_t)bc*PIX;
  float wv[9];
  #pragma unroll
  for(int i=0;i<9;++i) wv[i]=cw[c*9+i];
  float ks=gg[c]*rsqrtf(gv[c]+BEPS), kb=gb[c]-gm[c]*ks;
  int wb=wq*4;
  float o[4]={};
  #pragma unroll
  for(int dh=0;dh<3;++dh){ int hh=h+dh-1; if(hh<0||hh>63) continue;
    const unsigned short* row=src+hh*64;
    float rv[6];
    #pragma unroll
    for(int j=0;j<6;++j){ int wc=wb-1+j; rv[j]=(wc>=0&&wc<64)?b2f(row[wc]):0.f; }
    #pragma unroll
    for(int dw=0;dw<3;++dw){ float wgt=wv[dh*3+dw];
      #pragma unroll
      for(int i=0;i<4;++i) o[i]+=rv[i+dw]*wgt; } }
  float v0=fmaxf(o[0]*ks+kb,0.f), v1=fmaxf(o[1]*ks+kb,0.f);
  float v2=fmaxf(o[2]*ks+kb,0.f), v3=fmaxf(o[3]*ks+kb,0.f);
  uint2 pk; pk.x=pk2(v0,v1); pk.y=pk2(v2,v3);
  *(uint2*)&x2[(size_t)bc*PIX+h*64+wb]=pk;
}

// ---------------- k3: SE mean ----------------
__global__ __launch_bounds__(256) void k3(const unsigned short* __restrict__ x1,
  const unsigned short* __restrict__ x2,float* __restrict__ sr)
{
  int bc=blockIdx.x; int cg=bc&1023, b=bc>>10;
  const unsigned short* src=(cg<512)? x1+((size_t)b*512+cg)*PIX : x2+((size_t)b*512+cg-512)*PIX;
  float s=0;
  for(int i=threadIdx.x;i<512;i+=256){
    uint4 v=((const uint4*)src)[i];
    float a0,a1; unp2(v.x,a0,a1); s+=a0+a1;
    unp2(v.y,a0,a1); s+=a0+a1;
    unp2(v.z,a0,a1); s+=a0+a1;
    unp2(v.w,a0,a1); s+=a0+a1;
  }
  #pragma unroll
  for(int off=32;off;off>>=1) s+=__shfl_down(s,off);
  __shared__ float red[4];
  if((threadIdx.x&63)==0) red[threadIdx.x>>6]=s;
  __syncthreads();
  if(threadIdx.x==0) sr[bc]=(red[0]+red[1]+red[2]+red[3])*(1.f/4096.f);
}

// ---------------- k4: SE MLP ----------------
__global__ __launch_bounds__(256) void k4(const float* __restrict__ sr,const float* __restrict__ w1,
  const float* __restrict__ w2,float* __restrict__ sOut)
{
  int b=blockIdx.x;
  __shared__ float ls[1024];
  __shared__ float pm[4][64];
  __shared__ float mid[64];
  for(int i=threadIdx.x;i<1024;i+=256) ls[i]=sr[b*1024+i];
  __syncthreads();
  int k=threadIdx.x&63, part=threadIdx.x>>6;
  float p=0;
  for(int c=part*256;c<part*256+256;++c) p+=ls[c]*w1[k*1024+c];
  pm[part][k]=p;
  __syncthreads();
  if(threadIdx.x<64) mid[threadIdx.x]=fmaxf(pm[0][threadIdx.x]+pm[1][threadIdx.x]+pm[2][threadIdx.x]+pm[3][threadIdx.x],0.f);
  __syncthreads();
  for(int j=threadIdx.x;j<1024;j+=256){
    float a=0;
    for(int kk=0;kk<64;++kk) a+=mid[kk]*w2[j*64+kk];
    sOut[b*1024+j]=sigm(a);
  }
}

// ---------------- k5m: proj 1024->128 (SE in Wsb) + BN3 -> Fp, FpT bf16 [b][t][128] (swapped) ----------------
__global__ __launch_bounds__(256) void k5m(const unsigned short* __restrict__ x1,
  const unsigned short* __restrict__ x2,const unsigned short* __restrict__ Wsb,
  const float* __restrict__ g3,const float* __restrict__ b3,const float* __restrict__ m3,
  const float* __restrict__ v3,unsigned short* __restrict__ Fp,unsigned short* __restrict__ FpT)
{
  MF_PRE();
  __shared__ __align__(16) short sA[64*72];
  __shared__ __align__(16) short sW[64*72];
  const int m0=blockIdx.x*64, n0=blockIdx.y*64, b=blockIdx.z;
  const unsigned short* Wb=Wsb+(size_t)b*131072;
  f32x4 acc[2][2]={};
  for(int k0=0;k0<1024;k0+=64){
    { int c=k0+tk;
      const unsigned short* s_=(c<512)? x1+((size_t)b*512+c)*PIX : x2+((size_t)b*512+c-512)*PIX;
      STAGE_A_TR_BF16(s_+m0+tmb); }
    STAGE_W_BF(Wb,1024);
    __syncthreads();
    MF_STEP_SW();
    __syncthreads();
  }
  #pragma unroll
  for(int i=0;i<2;++i){ int oc0=n0+wn*32+i*16+fg*4;
    float4 g4=*(const float4*)&g3[oc0];
    float4 v4=*(const float4*)&v3[oc0];
    float4 m4=*(const float4*)&m3[oc0];
    float4 b4=*(const float4*)&b3[oc0];
    float ks0=g4.x*rsqrtf(v4.x+BEPS), kb0=b4.x-m4.x*ks0;
    float ks1=g4.y*rsqrtf(v4.y+BEPS), kb1=b4.y-m4.y*ks1;
    float ks2=g4.z*rsqrtf(v4.z+BEPS), kb2=b4.z-m4.z*ks2;
    float ks3=g4.w*rsqrtf(v4.w+BEPS), kb3=b4.w-m4.w*ks3;
    #pragma unroll
    for(int j=0;j<2;++j){ int pp=m0+wm*32+j*16+fr;
      uint2 pk;
      pk.x=pk2(acc[i][j][0]*ks0+kb0, acc[i][j][1]*ks1+kb1);
      pk.y=pk2(acc[i][j][2]*ks2+kb2, acc[i][j][3]*ks3+kb3);
      *(uint2*)&Fp[((size_t)b*PIX+pp)*128+oc0]=pk;
      int q=((pp&63)<<6)|(pp>>6);
      *(uint2*)&FpT[((size_t)b*PIX+q)*128+oc0]=pk; } }
}

// ---------------- k6am: in_proj 128->512 -> xsT, zT bf16 [n][t][256] (swapped) ----------------
__global__ __launch_bounds__(256) void k6am(const unsigned short* __restrict__ Fp,
  const unsigned short* __restrict__ FpT,const unsigned short* __restrict__ Winb,
  unsigned short* __restrict__ xsT,unsigned short* __restrict__ zT)
{
  MF_PRE();
  __shared__ __align__(16) short sA[64*72];
  __shared__ __align__(16) short sW[64*72];
  const int m0=blockIdx.x*64, n0=blockIdx.y*64, n=blockIdx.z;
  const int d=n>>3, b=n&7;
  const unsigned short* src=((d<2)?Fp:FpT)+(size_t)b*PIX*128;
  const int rev=(d&1)?63:0;
  f32x4 acc[2][2]={};
  for(int k0=0;k0<128;k0+=64){
    { int t=m0+srow; int tm=(t&~63)|((t&63)^rev);
      STAGE_A_TOK_BF(src+(size_t)tm*128+k0+sch*16); }
    STAGE_W_BF(Winb,128);
    __syncthreads();
    MF_STEP_SW();
    __syncthreads();
  }
  #pragma unroll
  for(int i=0;i<2;++i){ int r0=n0+wn*32+i*16+fg*4;
    unsigned short* dst; int row0; bool dosilu;
    if(r0<256){ dst=xsT; row0=r0; dosilu=false; } else { dst=zT; row0=r0-256; dosilu=true; }
    #pragma unroll
    for(int j=0;j<2;++j){ int tok=m0+wm*32+j*16+fr;
      float v0=acc[i][j][0],v1=acc[i][j][1],v2=acc[i][j][2],v3=acc[i][j][3];
      if(dosilu){ v0=silu_(v0); v1=silu_(v1); v2=silu_(v2); v3=silu_(v3); }
      uint2 pk; pk.x=pk2(v0,v1); pk.y=pk2(v2,v3);
      *(uint2*)&dst[((size_t)n*SEQL+tok)*256+row0]=pk; } }
}

// ---------------- k6b: causal conv1d (k=4) + SiLU (token-major) ----------------
__global__ __launch_bounds__(256) void k6b(const unsigned short* __restrict__ xsT,
  const float* __restrict__ cw,const float* __restrict__ cb,unsigned short* __restrict__ uT)
{
  int gid=blockIdx.x*256+threadIdx.x;
  int cb8=gid&31, tb=(gid>>5)&511, n=gid>>14;
  int c0=cb8*8, t0=tb*8;
  const unsigned short* base=xsT+(size_t)n*SEQL*256+c0;
  float w0[8],w1[8],w2[8],w3[8],bb[8];
  #pragma unroll
  for(int j=0;j<8;++j){ float4 wv=*(const float4*)&cw[(c0+j)*4];
    w0[j]=wv.x; w1[j]=wv.y; w2[j]=wv.z; w3[j]=wv.w; bb[j]=cb[c0+j]; }
  float ra[8],rb[8],rc[8],rd[8];
  #pragma unroll
  for(int j=0;j<8;++j){ ra[j]=0.f; rb[j]=0.f; rc[j]=0.f; }
  if(t0>=3){
    uint4 v;
    v=*(const uint4*)(base+(size_t)(t0-3)*256); unp2(v.x,ra[0],ra[1]);unp2(v.y,ra[2],ra[3]);unp2(v.z,ra[4],ra[5]);unp2(v.w,ra[6],ra[7]);
    v=*(const uint4*)(base+(size_t)(t0-2)*256); unp2(v.x,rb[0],rb[1]);unp2(v.y,rb[2],rb[3]);unp2(v.z,rb[4],rb[5]);unp2(v.w,rb[6],rb[7]);
    v=*(const uint4*)(base+(size_t)(t0-1)*256); unp2(v.x,rc[0],rc[1]);unp2(v.y,rc[2],rc[3]);unp2(v.z,rc[4],rc[5]);unp2(v.w,rc[6],rc[7]);
  }
  unsigned short* ob=uT+(size_t)n*SEQL*256+c0;
  for(int j=0;j<8;++j){
    uint4 v=*(const uint4*)(base+(size_t)(t0+j)*256);
    unp2(v.x,rd[0],rd[1]);unp2(v.y,rd[2],rd[3]);unp2(v.z,rd[4],rd[5]);unp2(v.w,rd[6],rd[7]);
    float o[8];
    #pragma unroll
    for(int q=0;q<8;++q){
      o[q]=silu_(ra[q]*w0[q]+rb[q]*w1[q]+rc[q]*w2[q]+rd[q]*w3[q]+bb[q]);
      ra[q]=rb[q]; rb[q]=rc[q]; rc[q]=rd[q];
    }
    uint4 ov; ov.x=pk2(o[0],o[1]); ov.y=pk2(o[2],o[3]); ov.z=pk2(o[4],o[5]); ov.w=pk2(o[6],o[7]);
    *(uint4*)(ob+(size_t)(t0+j)*256)=ov;
  }
}

// ---------------- k6cm: dt GEMM + bias + softplus -> dtT bf16 [n][t][256] (swapped) ----------------
__global__ __launch_bounds__(256) void k6cm(const unsigned short* __restrict__ uT,
  const unsigned short* __restrict__ Wcb,const float* __restrict__ dtb,
  unsigned short* __restrict__ dtT)
{
  MF_PRE();
  __shared__ __align__(16) short sA[64*72];
  __shared__ __align__(16) short sW[64*72];
  const int m0=blockIdx.x*64, n0=blockIdx.y*64, n=blockIdx.z;
  const unsigned short* ubase=uT+(size_t)n*SEQL*256;
  f32x4 acc[2][2]={};
  for(int k0=0;k0<256;k0+=64){
    STAGE_A_TOK_BF(ubase+(size_t)(m0+srow)*256+k0+sch*16);
    STAGE_W_BF(Wcb,256);
    __syncthreads();
    MF_STEP_SW();
    __syncthreads();
  }
  #pragma unroll
  for(int i=0;i<2;++i){ int oc0=n0+wn*32+i*16+fg*4;
    float4 bb4=*(const float4*)&dtb[oc0];
    #pragma unroll
    for(int j=0;j<2;++j){ int tok=m0+wm*32+j*16+fr;
      uint2 pk;
      pk.x=pk2(softplus_(acc[i][j][0]+bb4.x), softplus_(acc[i][j][1]+bb4.y));
      pk.y=pk2(softplus_(acc[i][j][2]+bb4.z), softplus_(acc[i][j][3]+bb4.w));
      *(uint2*)&dtT[((size_t)n*SEQL+tok)*256+oc0]=pk; } }
}

// ---------------- k6bc: Bc/Cc = u @ xpw[8:10].T (wave per token) ----------------
__global__ __launch_bounds__(256) void k6bc(const unsigned short* __restrict__ uT,
  const float* __restrict__ xpw,float* __restrict__ Bc,float* __restrict__ Cc)
{
  int inst=blockIdx.x*4+(threadIdx.x>>6);
  int ln=threadIdx.x&63;
  int n=inst>>12, t=inst&4095;
  const unsigned short* up=uT+((size_t)n*SEQL+t)*256+ln*4;
  uint2 uu=*(const uint2*)up;
  float u0,u1,u2,u3; unp2(uu.x,u0,u1); unp2(uu.y,u2,u3);
  float4 w8=*(const float4*)&xpw[8*256+ln*4];
  float4 w9=*(const float4*)&xpw[9*256+ln*4];
  float sb=u0*w8.x+u1*w8.y+u2*w8.z+u3*w8.w;
  float sc=u0*w9.x+u1*w9.y+u2*w9.z+u3*w9.w;
  #pragma unroll
  for(int off=32;off;off>>=1){ sb+=__shfl_xor(sb,off); sc+=__shfl_xor(sc,off); }
  if(ln==0){ Bc[(size_t)n*SEQL+t]=sb; Cc[(size_t)n*SEQL+t]=sc; }
}

// ---------------- k7: chunked scan, 32 chunks of 128, 4 channels/lane ----------------
__global__ __launch_bounds__(256) void k7p1(const unsigned short* __restrict__ uT,
  const unsigned short* __restrict__ dtT,const float* __restrict__ Bc,
  const float* __restrict__ A_log,float* __restrict__ Pq)
{
  int g=blockIdx.x*256+threadIdx.x;
  int cq=g&63, ch=(g>>6)&31, n=g>>11;
  int c0=cq*4;
  float A0=-__expf(A_log[c0]),A1=-__expf(A_log[c0+1]),A2=-__expf(A_log[c0+2]),A3=-__expf(A_log[c0+3]);
  size_t tbase=((size_t)n*SEQL+ch*128)*256+c0;
  const float* bp=Bc+(size_t)n*SEQL+ch*128;
  float P0=1,P1=1,P2=1,P3=1,q0=0,q1=0,q2=0,q3=0;
  for(int t=0;t<128;++t){
    uint2 uu=*(const uint2*)&uT[tbase+(size_t)t*256];
    uint2 dd=*(const uint2*)&dtT[tbase+(size_t)t*256];
    float u0,u1,u2,u3,d0,d1,d2,d3;
    unp2(uu.x,u0,u1); unp2(uu.y,u2,u3);
    unp2(dd.x,d0,d1); unp2(dd.y,d2,d3);
    float bv=bp[t];
    float e0=__expf(d0*A0),e1=__expf(d1*A1),e2=__expf(d2*A2),e3=__expf(d3*A3);
    q0=q0*e0+d0*bv*u0; q1=q1*e1+d1*bv*u1; q2=q2*e2+d2*bv*u2; q3=q3*e3+d3*bv*u3;
    P0*=e0; P1*=e1; P2*=e2; P3*=e3;
  }
  size_t o=(((size_t)n*256+c0)*32+ch)*2;
  Pq[o]=P0; Pq[o+1]=q0; Pq[o+64]=P1; Pq[o+65]=q1;
  Pq[o+128]=P2; Pq[o+129]=q2; Pq[o+192]=P3; Pq[o+193]=q3;
}

__global__ __launch_bounds__(256) void k7mid(const float* __restrict__ Pq,float* __restrict__ h0)
{
  int nc=blockIdx.x*256+threadIdx.x;
  float h=0.f;
  for(int ch=0;ch<32;++ch){
    h0[(size_t)nc*32+ch]=h;
    h=h*Pq[((size_t)nc*32+ch)*2]+Pq[((size_t)nc*32+ch)*2+1];
  }
}

__global__ __launch_bounds__(256) void k7p2(unsigned short* __restrict__ uT,
  const unsigned short* __restrict__ dtT,const unsigned short* __restrict__ zT,
  const float* __restrict__ Bc,const float* __restrict__ Cc,
  const float* __restrict__ A_log,const float* __restrict__ Dp,
  const float* __restrict__ h0)
{
  int g=blockIdx.x*256+threadIdx.x;
  int cq=g&63, ch=(g>>6)&31, n=g>>11;
  int c0=cq*4;
  float A0=-__expf(A_log[c0]),A1=-__expf(A_log[c0+1]),A2=-__expf(A_log[c0+2]),A3=-__expf(A_log[c0+3]);
  float D0=Dp[c0],D1=Dp[c0+1],D2=Dp[c0+2],D3=Dp[c0+3];
  size_t tbase=((size_t)n*SEQL+ch*128)*256+c0;
  const float* bp=Bc+(size_t)n*SEQL+ch*128;
  const float* cp=Cc+(size_t)n*SEQL+ch*128;
  size_t hb=((size_t)n*256+c0)*32+ch;
  float h0v=h0[hb],h1v=h0[hb+32],h2v=h0[hb+64],h3v=h0[hb+96];
  for(int t=0;t<128;++t){
    uint2 uu=*(const uint2*)&uT[tbase+(size_t)t*256];
    uint2 dd=*(const uint2*)&dtT[tbase+(size_t)t*256];
    uint2 zz=*(const uint2*)&zT[tbase+(size_t)t*256];
    float u0,u1,u2,u3,d0,d1,d2,d3,z0,z1,z2,z3;
    unp2(uu.x,u0,u1); unp2(uu.y,u2,u3);
    unp2(dd.x,d0,d1); unp2(dd.y,d2,d3);
    unp2(zz.x,z0,z1); unp2(zz.y,z2,z3);
    float bv=bp[t], cv=cp[t];
    float e0=__expf(d0*A0),e1=__expf(d1*A1),e2=__expf(d2*A2),e3=__expf(d3*A3);
    h0v=h0v*e0+d0*bv*u0; h1v=h1v*e1+d1*bv*u1; h2v=h2v*e2+d2*bv*u2; h3v=h3v*e3+d3*bv*u3;
    float y0=(h0v*cv+u0*D0)*z0, y1=(h1v*cv+u1*D1)*z1;
    float y2=(h2v*cv+u2*D2)*z2, y3=(h3v*cv+u3*D3)*z3;
    uint2 oo; oo.x=pk2(y0,y1); oo.y=pk2(y2,y3);
    *(uint2*)&uT[tbase+(size_t)t*256]=oo;
  }
}

// ---------------- k8am: out_proj 256->128 -> Y4 bf16 [n][t][128] (swapped) ----------------
__global__ __launch_bounds__(256) void k8am(const unsigned short* __restrict__ yT,
  const unsigned short* __restrict__ Woutb,unsigned short* __restrict__ Y4)
{
  MF_PRE();
  __shared__ __align__(16) short sA[64*72];
  __shared__ __align__(16) short sW[64*72];
  const int m0=blockIdx.x*64, n0=blockIdx.y*64, n=blockIdx.z;
  const unsigned short* ybase=yT+(size_t)n*SEQL*256;
  f32x4 acc[2][2]={};
  for(int k0=0;k0<256;k0+=64){
    STAGE_A_TOK_BF(ybase+(size_t)(m0+srow)*256+k0+sch*16);
    STAGE_W_BF(Woutb,256);
    __syncthreads();
    MF_STEP_SW();
    __syncthreads();
  }
  #pragma unroll
  for(int i=0;i<2;++i){ int oc0=n0+wn*32+i*16+fg*4;
    #pragma unroll
    for(int j=0;j<2;++j){ int tok=m0+wm*32+j*16+fr;
      uint2 pk;
      pk.x=pk2(acc[i][j][0],acc[i][j][1]);
      pk.y=pk2(acc[i][j][2],acc[i][j][3]);
      *(uint2*)&Y4[((size_t)n*SEQL+tok)*128+oc0]=pk; } }
}

// ---------------- k8bm: pi GEMM + gate + 4-dir sum -> ysum bf16 [b][t][128] (swapped) ----------------
__global__ __launch_bounds__(256) void k8bm(const unsigned short* __restrict__ Fp,
  const unsigned short* __restrict__ FpT,const unsigned short* __restrict__ Y4,
  const unsigned short* __restrict__ piwb,const float* __restrict__ pib,
  unsigned short* __restrict__ ysum)
{
  MF_PRE();
  __shared__ __align__(16) short sA[64*72];
  __shared__ __align__(16) short sW[64*72];
  const int m0=blockIdx.x*64, n0=blockIdx.y*64, b=blockIdx.z;
  f32x4 gs[2][2]={};
  for(int d=0;d<4;++d){
    const int n=d*8+b;
    const unsigned short* src=((d<2)?Fp:FpT)+(size_t)b*PIX*128;
    const unsigned short* Y4n=Y4+(size_t)n*SEQL*128;
    const int rev=(d&1)?63:0;
    f32x4 acc[2][2]={};
    for(int k0=0;k0<256;k0+=64){
      if(k0<128){
        int t=m0+srow; int tm=(t&~63)|((t&63)^rev);
        STAGE_A_TOK_BF(src+(size_t)tm*128+k0+sch*16);
      } else {
        STAGE_A_TOK_BF(Y4n+(size_t)(m0+srow)*128+(k0-128)+sch*16);
      }
      STAGE_W_BF(piwb,256);
      __syncthreads();
      MF_STEP_SW();
      __syncthreads();
    }
    #pragma unroll
    for(int i=0;i<2;++i){ int oc0=n0+wn*32+i*16+fg*4;
      float4 pb4=*(const float4*)&pib[oc0];
      #pragma unroll
      for(int j=0;j<2;++j){ int tok=m0+wm*32+j*16+fr;
        int tm=(tok&~63)|((tok&63)^rev);
        uint2 xv=*(const uint2*)&src[(size_t)tm*128+oc0];
        uint2 yv=*(const uint2*)&Y4n[(size_t)tok*128+oc0];
        float x0,x1v,x2v,x3v,y0,y1,y2,y3;
        unp2(xv.x,x0,x1v); unp2(xv.y,x2v,x3v);
        unp2(yv.x,y0,y1);  unp2(yv.y,y2,y3);
        float p0=sigm(acc[i][j][0]+pb4.x), p1=sigm(acc[i][j][1]+pb4.y);
        float p2=sigm(acc[i][j][2]+pb4.z), p3=sigm(acc[i][j][3]+pb4.w);
        gs[i][j][0]+=y0*p0+x0*(1.f-p0);
        gs[i][j][1]+=y1*p1+x1v*(1.f-p1);
        gs[i][j][2]+=y2*p2+x2v*(1.f-p2);
        gs[i][j][3]+=y3*p3+x3v*(1.f-p3);
      } }
  }
  #pragma unroll
  for(int i=0;i<2;++i){ int oc0=n0+wn*32+i*16+fg*4;
    #pragma unroll
    for(int j=0;j<2;++j){ int tok=m0+wm*32+j*16+fr;
      uint2 pk;
      pk.x=pk2(gs[i][j][0],gs[i][j][1]);
      pk.y=pk2(gs[i][j][2],gs[i][j][3]);
      *(uint2*)&ysum[((size_t)b*PIX+tok)*128+oc0]=pk; } }
}

// ---------------- k9m: final conv1x1 ((ysum+Fp) @ fw) -> out fp32 [b][c][t] ----------------
__global__ __launch_bounds__(256) void k9m(const unsigned short* __restrict__ ysum,
  const unsigned short* __restrict__ Fp,const unsigned short* __restrict__ fwb,
  float* __restrict__ out)
{
  MF_PRE();
  __shared__ __align__(16) short sA[64*72];
  __shared__ __align__(16) short sW[64*72];
  const int m0=blockIdx.x*64, n0=blockIdx.y*64, b=blockIdx.z;
  f32x4 acc[2][2]={};
  for(int k0=0;k0<128;k0+=64){
    { size_t off=((size_t)b*PIX+m0+srow)*128+k0+sch*16;
      STAGE_A_SUM_BF(ysum+off,Fp+off); }
    STAGE_W_BF(fwb,128);
    __syncthreads();
    MF_STEP();
    __syncthreads();
  }
  #pragma unroll
  for(int jn=0;jn<2;++jn){ int oc=n0+wn*32+jn*16+fr;
    #pragma unroll
    for(int i=0;i<2;++i){ int mb=m0+wm*32+i*16+fg*4;
      *(float4*)&out[((size_t)b*128+oc)*PIX+mb]=
        make_float4(acc[i][jn][0],acc[i][jn][1],acc[i][jn][2],acc[i][jn][3]); } }
}

extern "C" void kernel_launch(void* const* d_in,const int* in_sizes,int n_in,
  void* d_out,int out_size,void* d_ws,size_t ws_size,hipStream_t stream)
{
  (void)in_sizes; (void)n_in; (void)out_size; (void)ws_size;
  const float* FT1=(const float*)d_in[0];
  const float* FT2=(const float*)d_in[1];
  const float* gpw=(const float*)d_in[2];
  const float* g1g=(const float*)d_in[3];
  const float* g1b=(const float*)d_in[4];
  const float* g1m=(const float*)d_in[5];
  const float* g1v=(const float*)d_in[6];
  const float* gcw=(const float*)d_in[7];
  const float* g2g=(const float*)d_in[8];
  const float* g2b=(const float*)d_in[9];
  const float* g2m=(const float*)d_in[10];
  const float* g2v=(const float*)d_in[11];
  const float* sw1=(const float*)d_in[12];
  const float* sw2=(const float*)d_in[13];
  const float* prw=(const float*)d_in[14];
  const float* b3g=(const float*)d_in[15];
  const float* b3b=(const float*)d_in[16];
  const float* b3m=(const float*)d_in[17];
  const float* b3v=(const float*)d_in[18];
  const float* ipw=(const float*)d_in[19];
  const float* c1w=(const float*)d_in[20];
  const float* c1b=(const float*)d_in[21];
  const float* xpw=(const float*)d_in[22];
  const float* dtw=(const float*)d_in[23];
  const float* dtb=(const float*)d_in[24];
  const float* Alog=(const float*)d_in[25];
  const float* Dp=(const float*)d_in[26];
  const float* opw=(const float*)d_in[27];
  const float* piw=(const float*)d_in[28];
  const float* pib=(const float*)d_in[29];
  const float* fw=(const float*)d_in[30];

  char* w=(char*)d_ws;
  const size_t MB=1ull<<20;
  unsigned short* x1b =(unsigned short*)(w);            // 32MB bf16 [b][c][t]
  unsigned short* x2b =(unsigned short*)(w+32*MB);      // 32MB
  unsigned short* uT  =(unsigned short*)(w);            // 64MB [n][t][256] (after k5m)
  unsigned short* xsT =(unsigned short*)(w+64*MB);      // 64MB [n][t][256]
  unsigned short* dtT =(unsigned short*)(w+64*MB);      // 64MB (after k6b)
  unsigned short* Y4  =(unsigned short*)(w+64*MB);      // 32MB (after k7p2)
  unsigned short* zT  =(unsigned short*)(w+128*MB);     // 64MB [n][t][256]
  unsigned short* Fpb =(unsigned short*)(w+192*MB);     // 8MB  [b][t][128]
  unsigned short* FpTb=(unsigned short*)(w+200*MB);     // 8MB
  unsigned short* ysb =(unsigned short*)(w+208*MB);     // 8MB
  float* Bc =(float*)(w+216*MB);                        // 512KB
  float* Cc =(float*)(w+216*MB+512*1024);               // 512KB
  float* sr =(float*)(w+217*MB);                        // 32KB
  float* sse=(float*)(w+217*MB+32*1024);                // 32KB
  float* Pq =(float*)(w+218*MB);                        // 2MB
  float* h0 =(float*)(w+220*MB);                        // 1MB
  unsigned short* Wcb =(unsigned short*)(w+221*MB);     // 128KB
  unsigned short* gpwb=(unsigned short*)(w+222*MB);     // 256KB
  unsigned short* ipwb=(unsigned short*)(w+223*MB);     // 128KB
  unsigned short* opwb=(unsigned short*)(w+224*MB);     // 64KB
  unsigned short* piwb=(unsigned short*)(w+224*MB+64*1024); // 64KB
  unsigned short* fwb =(unsigned short*)(w+224*MB+128*1024);// 32KB
  unsigned short* Wsb =(unsigned short*)(w+225*MB);     // 2MB

  kWb<<<512,256,0,stream>>>(gpw,ipw,opw,piw,fw,gpwb,ipwb,opwb,piwb,fwb);
  kWc<<<256,256,0,stream>>>(dtw,xpw,Wcb);
  k1m<<<dim3(64,8,8),256,0,stream>>>(FT1,FT2,gpwb,g1g,g1b,g1m,g1v,x1b);
  k2<<<16384,256,0,stream>>>(x1b,gcw,g2g,g2b,g2m,g2v,x2b);
  k3<<<8192,256,0,stream>>>(x1b,x2b,sr);
  k4<<<8,256,0,stream>>>(sr,sw1,sw2,sse);
  kWse<<<4096,256,0,stream>>>(prw,sse,Wsb);
  k5m<<<dim3(64,2,8),256,0,stream>>>(x1b,x2b,Wsb,b3g,b3b,b3m,b3v,Fpb,FpTb);
  k6am<<<dim3(64,8,32),256,0,stream>>>(Fpb,FpTb,ipwb,xsT,zT);
  k6b<<<2048,256,0,stream>>>(xsT,c1w,c1b,uT);
  k6cm<<<dim3(64,4,32),256,0,stream>>>(uT,Wcb,dtb,dtT);
  k6bc<<<32768,256,0,stream>>>(uT,xpw,Bc,Cc);
  k7p1<<<256,256,0,stream>>>(uT,dtT,Bc,Alog,Pq);
  k7mid<<<32,256,0,stream>>>(Pq,h0);
  k7p2<<<256,256,0,stream>>>(uT,dtT,zT,Bc,Cc,Alog,Dp,h0);
  k8am<<<dim3(64,2,32),256,0,stream>>>(uT,opwb,Y4);
  k8bm<<<dim3(64,2,8),256,0,stream>>>(Fpb,FpTb,Y4,piwb,pib,ysb);
  k9m<<<dim3(64,2,8),256,0,stream>>>(ysb,Fpb,fwb,(float*)d_out);
}

// Round 9
// 569.396 us; speedup vs baseline: 1.4852x; 1.0425x over previous
//
#include <hip/hip_runtime.h>
#include <hip/hip_bf16.h>

#define DEV static __device__ __forceinline__

#define PIX 4096
#define SEQL 4096
#define BEPS 1e-5f

DEV float b2f(unsigned short u){ unsigned int i=((unsigned int)u)<<16; float f; __builtin_memcpy(&f,&i,4); return f; }
DEV unsigned short f2b(float f){ __hip_bfloat16 h=__float2bfloat16(f); unsigned short s; __builtin_memcpy(&s,&h,2); return s; }
DEV short f2bs(float f){ return (short)f2b(f); }
DEV void unp2(unsigned int w, float&a, float&b){ unsigned int lo=w<<16, hi=w&0xffff0000u; __builtin_memcpy(&a,&lo,4); __builtin_memcpy(&b,&hi,4); }
DEV unsigned int pk2(float a,float b){ return (unsigned int)f2b(a)|((unsigned int)f2b(b)<<16); }
DEV float sigm(float x){ return 1.f/(1.f+__expf(-x)); }
DEV float silu_(float x){ return x*sigm(x); }
DEV float softplus_(float x){ return (x>15.f)?x:__logf(1.f+__expf(x)); }

using short8 = __attribute__((ext_vector_type(8))) short;
using f32x4  = __attribute__((ext_vector_type(4))) float;
#define MFMA16 __builtin_amdgcn_mfma_f32_16x16x32_bf16

// ================= MFMA GEMM skeleton =================
// tile 64(M) x 64(N) x 64(K), 256 threads = 4 waves (2x2), 2x2 16x16x32 frags/wave.
// sA/sW: [row][k] (72 shorts/row), chunk-XOR swizzle:
//   element (r,k) at r*72 + (((k>>4)^(r&3))<<4) + (k&15)
// D-layout invariant (verified R3/R4): D rows (fg*4+reg) index the FIRST operand's
// row-range; D cols (fr) index the SECOND operand's row-range.

#define MF_PRE() \
  const int tid=threadIdx.x; \
  const int lane=tid&63, wid=tid>>6; \
  const int wm=wid&1, wn=wid>>1; \
  const int fr=lane&15, fg=lane>>4; \
  const int srow=tid>>2, sch=tid&3; \
  const int tk=tid&63, tmb=(tid>>6)*16;

#define STAGE_A_TOK_BF(PTR) { \
  const unsigned short* ap_=(PTR); \
  uint4 q0_=*(const uint4*)ap_, q1_=*(const uint4*)(ap_+8); \
  int base_=srow*72+((sch^(srow&3))*16); \
  *(uint4*)&sA[base_]=q0_; *(uint4*)&sA[base_+8]=q1_; }

#define STAGE_A_SUM_BF(P1,P2) { \
  const unsigned short* p1_=(P1); const unsigned short* p2_=(P2); \
  unsigned short h1[16],h2[16]; \
  *(uint4*)&h1[0]=*(const uint4*)p1_; *(uint4*)&h1[8]=*(const uint4*)(p1_+8); \
  *(uint4*)&h2[0]=*(const uint4*)p2_; *(uint4*)&h2[8]=*(const uint4*)(p2_+8); \
  union { short h[16]; uint4 q[2]; } tmpa; \
  _Pragma("unroll") for(int j=0;j<16;++j) tmpa.h[j]=f2bs(b2f(h1[j])+b2f(h2[j])); \
  int base_=srow*72+((sch^(srow&3))*16); \
  *(uint4*)&sA[base_]=tmpa.q[0]; *(uint4*)&sA[base_+8]=tmpa.q[1]; }

#define STAGE_A_TR_F32(EXPR16) { \
  float tv[16]; \
  _Pragma("unroll") for(int j=0;j<16;++j) tv[j]=(EXPR16); \
  _Pragma("unroll") for(int j=0;j<16;++j){ int m_=tmb+j; \
    sA[m_*72+(((tk>>4)^(m_&3))<<4)+(tk&15)]=f2bs(tv[j]); } }

#define STAGE_A_TR_BF16(PTR) { \
  const unsigned short* ap_=(PTR); \
  unsigned short hv[16]; \
  *(uint4*)&hv[0]=*(const uint4*)ap_; *(uint4*)&hv[8]=*(const uint4*)(ap_+8); \
  _Pragma("unroll") for(int j=0;j<16;++j){ int m_=tmb+j; \
    sA[m_*72+(((tk>>4)^(m_&3))<<4)+(tk&15)]=(short)hv[j]; } }

#define STAGE_W_BF(PTR,LDK) { \
  const unsigned short* wp_=(PTR)+(size_t)(n0+srow)*(LDK)+k0+sch*16; \
  uint4 q0_=*(const uint4*)wp_, q1_=*(const uint4*)(wp_+8); \
  int sw_=((sch^(srow&3))*16); \
  *(uint4*)&sW[srow*72+sw_]=q0_; *(uint4*)&sW[srow*72+sw_+8]=q1_; }

// normal: first operand = sA (tokens/pixels), D rows = M
#define MF_STEP() \
  _Pragma("unroll") \
  for(int kk=0;kk<64;kk+=32){ \
    short8 af[2],bfv[2]; const int kq_=kk+fg*8; \
    _Pragma("unroll") for(int i=0;i<2;++i){ int ml=wm*32+i*16+fr; \
      af[i]=*(const short8*)&sA[ml*72+(((kq_>>4)^(ml&3))<<4)+(kq_&15)]; } \
    _Pragma("unroll") for(int jn=0;jn<2;++jn){ int nl=wn*32+jn*16+fr; \
      bfv[jn]=*(const short8*)&sW[nl*72+(((kq_>>4)^(nl&3))<<4)+(kq_&15)]; } \
    _Pragma("unroll") for(int i=0;i<2;++i) \
      _Pragma("unroll") for(int jn=0;jn<2;++jn) \
        acc[i][jn]=MFMA16(af[i],bfv[jn],acc[i][jn],0,0,0); }

// swapped: first operand = sW (channels) -> lane holds 4 consecutive channels
// at one token => uint2 epilogue stores. acc[i][j]: i=channel frag, j=token frag.
#define MF_STEP_SW() \
  _Pragma("unroll") \
  for(int kk=0;kk<64;kk+=32){ \
    short8 tf[2],wf[2]; const int kq_=kk+fg*8; \
    _Pragma("unroll") for(int j=0;j<2;++j){ int ml=wm*32+j*16+fr; \
      tf[j]=*(const short8*)&sA[ml*72+(((kq_>>4)^(ml&3))<<4)+(kq_&15)]; } \
    _Pragma("unroll") for(int i=0;i<2;++i){ int nl=wn*32+i*16+fr; \
      wf[i]=*(const short8*)&sW[nl*72+(((kq_>>4)^(nl&3))<<4)+(kq_&15)]; } \
    _Pragma("unroll") for(int i=0;i<2;++i) \
      _Pragma("unroll") for(int j=0;j<2;++j) \
        acc[i][j]=MFMA16(wf[i],tf[j],acc[i][j],0,0,0); }

// ---------------- weight prep ----------------
__global__ __launch_bounds__(256) void kWb(const float* __restrict__ g,const float* __restrict__ ip,
  const float* __restrict__ op,const float* __restrict__ pw,const float* __restrict__ f,
  unsigned short* __restrict__ gb,unsigned short* __restrict__ ib,unsigned short* __restrict__ ob,
  unsigned short* __restrict__ pb,unsigned short* __restrict__ fb)
{
  int x=blockIdx.x*256+threadIdx.x;
  if(x<131072) gb[x]=f2b(g[x]);
  if(x<65536)  ib[x]=f2b(ip[x]);
  if(x<32768){ ob[x]=f2b(op[x]); pb[x]=f2b(pw[x]); }
  if(x<16384)  fb[x]=f2b(f[x]);
}

__global__ __launch_bounds__(256) void kWc(const float* __restrict__ dtw,const float* __restrict__ xpw,
  unsigned short* __restrict__ Wcb)
{
  int c=blockIdx.x, k=threadIdx.x;
  float a=0.f;
  #pragma unroll
  for(int i=0;i<8;++i) a+=dtw[c*8+i]*xpw[i*256+k];
  Wcb[c*256+k]=f2b(a);
}

__global__ __launch_bounds__(256) void kWse(const float* __restrict__ prw,const float* __restrict__ sse,
  unsigned short* __restrict__ Wsb)
{
  int idx=blockIdx.x*256+threadIdx.x;
  int b=idx>>17, r=idx&131071, oc=r>>10, c=r&1023;
  Wsb[idx]=f2b(prw[(size_t)oc*1024+c]*sse[b*1024+c]);
}

// ---------------- k1m: conv1x1 256->512 + BN + ReLU -> x1 bf16 [b][c][t] ----------------
__global__ __launch_bounds__(256) void k1m(const float* __restrict__ FT1,const float* __restrict__ FT2,
  const unsigned short* __restrict__ Wpb,const float* __restrict__ gg,const float* __restrict__ gb,
  const float* __restrict__ gm,const float* __restrict__ gv,unsigned short* __restrict__ x1)
{
  MF_PRE();
  __shared__ __align__(16) short sA[64*72];
  __shared__ __align__(16) short sW[64*72];
  const int m0=blockIdx.x*64, n0=blockIdx.y*64, b=blockIdx.z;
  f32x4 acc[2][2]={};
  for(int k0=0;k0<256;k0+=64){
    { int c=k0+tk;
      const float* s_=(c<128)? FT1+((size_t)b*128+c)*PIX : FT2+((size_t)b*128+c-128)*PIX;
      const float* ap=s_+m0+tmb;
      STAGE_A_TR_F32(ap[j]); }
    STAGE_W_BF(Wpb,256);
    __syncthreads();
    MF_STEP();
    __syncthreads();
  }
  #pragma unroll
  for(int jn=0;jn<2;++jn){ int oc=n0+wn*32+jn*16+fr;
    float ks=gg[oc]*rsqrtf(gv[oc]+BEPS), kb=gb[oc]-gm[oc]*ks;
    #pragma unroll
    for(int i=0;i<2;++i){ int mb=m0+wm*32+i*16+fg*4;
      float v0=fmaxf(acc[i][jn][0]*ks+kb,0.f), v1=fmaxf(acc[i][jn][1]*ks+kb,0.f);
      float v2=fmaxf(acc[i][jn][2]*ks+kb,0.f), v3=fmaxf(acc[i][jn][3]*ks+kb,0.f);
      uint2 pk; pk.x=pk2(v0,v1); pk.y=pk2(v2,v3);
      *(uint2*)&x1[((size_t)b*512+oc)*PIX+mb]=pk; } }
}

// ---------------- k2: depthwise 3x3 + BN + ReLU (bf16) ----------------
__global__ __launch_bounds__(256) void k2(const unsigned short* __restrict__ x1,const float* __restrict__ cw,
  const float* __restrict__ gg,const float* __restrict__ gb,const float* __restrict__ gm,
  const float* __restrict__ gv,unsigned short* __restrict__ x2)
{
  int gid=blockIdx.x*256+threadIdx.x;
  int wq=gid&15, h=(gid>>4)&63, bc=gid>>10;
  int c=bc&511;
  const unsigned short* src=x1+(size_t)bc*PIX;
  float wv[9];
  #pragma unroll
  for(int i=0;i<9;++i) wv[i]=cw[c*9+i];
  float ks=gg[c]*rsqrtf(gv[c]+BEPS), kb=gb[c]-gm[c]*ks;
  int wb=wq*4;
  float o[4]={};
  #pragma unroll
  for(int dh=0;dh<3;++dh){ int hh=h+dh-1; if(hh<0||hh>63) continue;
    const unsigned short* row=src+hh*64;
    float rv[6];
    #pragma unroll
    for(int j=0;j<6;++j){ int wc=wb-1+j; rv[j]=(wc>=0&&wc<64)?b2f(row[wc]):0.f; }
    #pragma unroll
    for(int dw=0;dw<3;++dw){ float wgt=wv[dh*3+dw];
      #pragma unroll
      for(int i=0;i<4;++i) o[i]+=rv[i+dw]*wgt; } }
  float v0=fmaxf(o[0]*ks+kb,0.f), v1=fmaxf(o[1]*ks+kb,0.f);
  float v2=fmaxf(o[2]*ks+kb,0.f), v3=fmaxf(o[3]*ks+kb,0.f);
  uint2 pk; pk.x=pk2(v0,v1); pk.y=pk2(v2,v3);
  *(uint2*)&x2[(size_t)bc*PIX+h*64+wb]=pk;
}

// ---------------- k3: SE mean ----------------
__global__ __launch_bounds__(256) void k3(const unsigned short* __restrict__ x1,
  const unsigned short* __restrict__ x2,float* __restrict__ sr)
{
  int bc=blockIdx.x; int cg=bc&1023, b=bc>>10;
  const unsigned short* src=(cg<512)? x1+((size_t)b*512+cg)*PIX : x2+((size_t)b*512+cg-512)*PIX;
  float s=0;
  for(int i=threadIdx.x;i<512;i+=256){
    uint4 v=((const uint4*)src)[i];
    float a0,a1; unp2(v.x,a0,a1); s+=a0+a1;
    unp2(v.y,a0,a1); s+=a0+a1;
    unp2(v.z,a0,a1); s+=a0+a1;
    unp2(v.w,a0,a1); s+=a0+a1;
  }
  #pragma unroll
  for(int off=32;off;off>>=1) s+=__shfl_down(s,off);
  __shared__ float red[4];
  if((threadIdx.x&63)==0) red[threadIdx.x>>6]=s;
  __syncthreads();
  if(threadIdx.x==0) sr[bc]=(red[0]+red[1]+red[2]+red[3])*(1.f/4096.f);
}

// ---------------- k4: SE MLP ----------------
__global__ __launch_bounds__(256) void k4(const float* __restrict__ sr,const float* __restrict__ w1,
  const float* __restrict__ w2,float* __restrict__ sOut)
{
  int b=blockIdx.x;
  __shared__ float ls[1024];
  __shared__ float pm[4][64];
  __shared__ float mid[64];
  for(int i=threadIdx.x;i<1024;i+=256) ls[i]=sr[b*1024+i];
  __syncthreads();
  int k=threadIdx.x&63, part=threadIdx.x>>6;
  float p=0;
  for(int c=part*256;c<part*256+256;++c) p+=ls[c]*w1[k*1024+c];
  pm[part][k]=p;
  __syncthreads();
  if(threadIdx.x<64) mid[threadIdx.x]=fmaxf(pm[0][threadIdx.x]+pm[1][threadIdx.x]+pm[2][threadIdx.x]+pm[3][threadIdx.x],0.f);
  __syncthreads();
  for(int j=threadIdx.x;j<1024;j+=256){
    float a=0;
    for(int kk=0;kk<64;++kk) a+=mid[kk]*w2[j*64+kk];
    sOut[b*1024+j]=sigm(a);
  }
}

// ---------------- k5m: proj 1024->128 (SE in Wsb) + BN3 -> Fp, FpT bf16 [b][t][128] (swapped) ----------------
__global__ __launch_bounds__(256) void k5m(const unsigned short* __restrict__ x1,
  const unsigned short* __restrict__ x2,const unsigned short* __restrict__ Wsb,
  const float* __restrict__ g3,const float* __restrict__ b3,const float* __restrict__ m3,
  const float* __restrict__ v3,unsigned short* __restrict__ Fp,unsigned short* __restrict__ FpT)
{
  MF_PRE();
  __shared__ __align__(16) short sA[64*72];
  __shared__ __align__(16) short sW[64*72];
  const int m0=blockIdx.x*64, n0=blockIdx.y*64, b=blockIdx.z;
  const unsigned short* Wb=Wsb+(size_t)b*131072;
  f32x4 acc[2][2]={};
  for(int k0=0;k0<1024;k0+=64){
    { int c=k0+tk;
      const unsigned short* s_=(c<512)? x1+((size_t)b*512+c)*PIX : x2+((size_t)b*512+c-512)*PIX;
      STAGE_A_TR_BF16(s_+m0+tmb); }
    STAGE_W_BF(Wb,1024);
    __syncthreads();
    MF_STEP_SW();
    __syncthreads();
  }
  #pragma unroll
  for(int i=0;i<2;++i){ int oc0=n0+wn*32+i*16+fg*4;
    float4 g4=*(const float4*)&g3[oc0];
    float4 v4=*(const float4*)&v3[oc0];
    float4 m4=*(const float4*)&m3[oc0];
    float4 b4=*(const float4*)&b3[oc0];
    float ks0=g4.x*rsqrtf(v4.x+BEPS), kb0=b4.x-m4.x*ks0;
    float ks1=g4.y*rsqrtf(v4.y+BEPS), kb1=b4.y-m4.y*ks1;
    float ks2=g4.z*rsqrtf(v4.z+BEPS), kb2=b4.z-m4.z*ks2;
    float ks3=g4.w*rsqrtf(v4.w+BEPS), kb3=b4.w-m4.w*ks3;
    #pragma unroll
    for(int j=0;j<2;++j){ int pp=m0+wm*32+j*16+fr;
      uint2 pk;
      pk.x=pk2(acc[i][j][0]*ks0+kb0, acc[i][j][1]*ks1+kb1);
      pk.y=pk2(acc[i][j][2]*ks2+kb2, acc[i][j][3]*ks3+kb3);
      *(uint2*)&Fp[((size_t)b*PIX+pp)*128+oc0]=pk;
      int q=((pp&63)<<6)|(pp>>6);
      *(uint2*)&FpT[((size_t)b*PIX+q)*128+oc0]=pk; } }
}

// ---------------- k6am: in_proj 128->512 -> xs2, z2 bf16 [s][t][256], s = layout*8+b (16 streams) ----------------
__global__ __launch_bounds__(256) void k6am(const unsigned short* __restrict__ Fp,
  const unsigned short* __restrict__ FpT,const unsigned short* __restrict__ Winb,
  unsigned short* __restrict__ xs2,unsigned short* __restrict__ z2)
{
  MF_PRE();
  __shared__ __align__(16) short sA[64*72];
  __shared__ __align__(16) short sW[64*72];
  const int m0=blockIdx.x*64, n0=blockIdx.y*64, s=blockIdx.z;
  const int l=s>>3, b=s&7;
  const unsigned short* src=(l?FpT:Fp)+(size_t)b*PIX*128;
  f32x4 acc[2][2]={};
  for(int k0=0;k0<128;k0+=64){
    STAGE_A_TOK_BF(src+(size_t)(m0+srow)*128+k0+sch*16);
    STAGE_W_BF(Winb,128);
    __syncthreads();
    MF_STEP_SW();
    __syncthreads();
  }
  #pragma unroll
  for(int i=0;i<2;++i){ int r0=n0+wn*32+i*16+fg*4;
    unsigned short* dst; int row0; bool dosilu;
    if(r0<256){ dst=xs2; row0=r0; dosilu=false; } else { dst=z2; row0=r0-256; dosilu=true; }
    #pragma unroll
    for(int j=0;j<2;++j){ int tok=m0+wm*32+j*16+fr;
      float v0=acc[i][j][0],v1=acc[i][j][1],v2=acc[i][j][2],v3=acc[i][j][3];
      if(dosilu){ v0=silu_(v0); v1=silu_(v1); v2=silu_(v2); v3=silu_(v3); }
      uint2 pk; pk.x=pk2(v0,v1); pk.y=pk2(v2,v3);
      *(uint2*)&dst[((size_t)s*SEQL+tok)*256+row0]=pk; } }
}

// ---------------- k6b: causal conv1d (k=4) + SiLU; reads shared xs2 via direction map ----------------
__global__ __launch_bounds__(256) void k6b(const unsigned short* __restrict__ xs2,
  const float* __restrict__ cw,const float* __restrict__ cb,unsigned short* __restrict__ uT)
{
  int gid=blockIdx.x*256+threadIdx.x;
  int cb8=gid&31, tb=(gid>>5)&511, n=gid>>14;
  int d=n>>3, b=n&7, l=d>>1, odd=d&1, s=l*8+b;
  int c0=cb8*8, t0=tb*8;
  const unsigned short* base=xs2+(size_t)s*SEQL*256+c0;
  float w0[8],w1[8],w2[8],w3[8],bb[8];
  #pragma unroll
  for(int j=0;j<8;++j){ float4 wv=*(const float4*)&cw[(c0+j)*4];
    w0[j]=wv.x; w1[j]=wv.y; w2[j]=wv.z; w3[j]=wv.w; bb[j]=cb[c0+j]; }
  float ra[8],rb[8],rc[8],rd[8];
  #pragma unroll
  for(int j=0;j<8;++j){ ra[j]=0.f; rb[j]=0.f; rc[j]=0.f; }
  #define XROW(T) (odd? (((T)&~63)|(((T)&63)^63)) : (T))
  if(t0>=3){
    uint4 v;
    v=*(const uint4*)(base+(size_t)XROW(t0-3)*256); unp2(v.x,ra[0],ra[1]);unp2(v.y,ra[2],ra[3]);unp2(v.z,ra[4],ra[5]);unp2(v.w,ra[6],ra[7]);
    v=*(const uint4*)(base+(size_t)XROW(t0-2)*256); unp2(v.x,rb[0],rb[1]);unp2(v.y,rb[2],rb[3]);unp2(v.z,rb[4],rb[5]);unp2(v.w,rb[6],rb[7]);
    v=*(const uint4*)(base+(size_t)XROW(t0-1)*256); unp2(v.x,rc[0],rc[1]);unp2(v.y,rc[2],rc[3]);unp2(v.z,rc[4],rc[5]);unp2(v.w,rc[6],rc[7]);
  }
  unsigned short* ob=uT+(size_t)n*SEQL*256+c0;
  for(int j=0;j<8;++j){
    uint4 v=*(const uint4*)(base+(size_t)XROW(t0+j)*256);
    unp2(v.x,rd[0],rd[1]);unp2(v.y,rd[2],rd[3]);unp2(v.z,rd[4],rd[5]);unp2(v.w,rd[6],rd[7]);
    float o[8];
    #pragma unroll
    for(int q=0;q<8;++q){
      o[q]=silu_(ra[q]*w0[q]+rb[q]*w1[q]+rc[q]*w2[q]+rd[q]*w3[q]+bb[q]);
      ra[q]=rb[q]; rb[q]=rc[q]; rc[q]=rd[q];
    }
    uint4 ov; ov.x=pk2(o[0],o[1]); ov.y=pk2(o[2],o[3]); ov.z=pk2(o[4],o[5]); ov.w=pk2(o[6],o[7]);
    *(uint4*)(ob+(size_t)(t0+j)*256)=ov;
  }
  #undef XROW
}

// ---------------- k6cm: dt GEMM + bias + softplus -> dtT bf16 [n][t][256] (swapped) ----------------
__global__ __launch_bounds__(256) void k6cm(const unsigned short* __restrict__ uT,
  const unsigned short* __restrict__ Wcb,const float* __restrict__ dtb,
  unsigned short* __restrict__ dtT)
{
  MF_PRE();
  __shared__ __align__(16) short sA[64*72];
  __shared__ __align__(16) short sW[64*72];
  const int m0=blockIdx.x*64, n0=blockIdx.y*64, n=blockIdx.z;
  const unsigned short* ubase=uT+(size_t)n*SEQL*256;
  f32x4 acc[2][2]={};
  for(int k0=0;k0<256;k0+=64){
    STAGE_A_TOK_BF(ubase+(size_t)(m0+srow)*256+k0+sch*16);
    STAGE_W_BF(Wcb,256);
    __syncthreads();
    MF_STEP_SW();
    __syncthreads();
  }
  #pragma unroll
  for(int i=0;i<2;++i){ int oc0=n0+wn*32+i*16+fg*4;
    float4 bb4=*(const float4*)&dtb[oc0];
    #pragma unroll
    for(int j=0;j<2;++j){ int tok=m0+wm*32+j*16+fr;
      uint2 pk;
      pk.x=pk2(softplus_(acc[i][j][0]+bb4.x), softplus_(acc[i][j][1]+bb4.y));
      pk.y=pk2(softplus_(acc[i][j][2]+bb4.z), softplus_(acc[i][j][3]+bb4.w));
      *(uint2*)&dtT[((size_t)n*SEQL+tok)*256+oc0]=pk; } }
}

// ---------------- k6bc: Bc/Cc = u @ xpw[8:10].T (wave per token) ----------------
__global__ __launch_bounds__(256) void k6bc(const unsigned short* __restrict__ uT,
  const float* __restrict__ xpw,float* __restrict__ Bc,float* __restrict__ Cc)
{
  int inst=blockIdx.x*4+(threadIdx.x>>6);
  int ln=threadIdx.x&63;
  int n=inst>>12, t=inst&4095;
  const unsigned short* up=uT+((size_t)n*SEQL+t)*256+ln*4;
  uint2 uu=*(const uint2*)up;
  float u0,u1,u2,u3; unp2(uu.x,u0,u1); unp2(uu.y,u2,u3);
  float4 w8=*(const float4*)&xpw[8*256+ln*4];
  float4 w9=*(const float4*)&xpw[9*256+ln*4];
  float sb=u0*w8.x+u1*w8.y+u2*w8.z+u3*w8.w;
  float sc=u0*w9.x+u1*w9.y+u2*w9.z+u3*w9.w;
  #pragma unroll
  for(int off=32;off;off>>=1){ sb+=__shfl_xor(sb,off); sc+=__shfl_xor(sc,off); }
  if(ln==0){ Bc[(size_t)n*SEQL+t]=sb; Cc[(size_t)n*SEQL+t]=sc; }
}

// ---------------- k7: chunked scan, 32 chunks of 128, 4 channels/lane ----------------
__global__ __launch_bounds__(256) void k7p1(const unsigned short* __restrict__ uT,
  const unsigned short* __restrict__ dtT,const float* __restrict__ Bc,
  const float* __restrict__ A_log,float* __restrict__ Pq)
{
  int g=blockIdx.x*256+threadIdx.x;
  int cq=g&63, ch=(g>>6)&31, n=g>>11;
  int c0=cq*4;
  float A0=-__expf(A_log[c0]),A1=-__expf(A_log[c0+1]),A2=-__expf(A_log[c0+2]),A3=-__expf(A_log[c0+3]);
  size_t tbase=((size_t)n*SEQL+ch*128)*256+c0;
  const float* bp=Bc+(size_t)n*SEQL+ch*128;
  float P0=1,P1=1,P2=1,P3=1,q0=0,q1=0,q2=0,q3=0;
  for(int t=0;t<128;++t){
    uint2 uu=*(const uint2*)&uT[tbase+(size_t)t*256];
    uint2 dd=*(const uint2*)&dtT[tbase+(size_t)t*256];
    float u0,u1,u2,u3,d0,d1,d2,d3;
    unp2(uu.x,u0,u1); unp2(uu.y,u2,u3);
    unp2(dd.x,d0,d1); unp2(dd.y,d2,d3);
    float bv=bp[t];
    float e0=__expf(d0*A0),e1=__expf(d1*A1),e2=__expf(d2*A2),e3=__expf(d3*A3);
    q0=q0*e0+d0*bv*u0; q1=q1*e1+d1*bv*u1; q2=q2*e2+d2*bv*u2; q3=q3*e3+d3*bv*u3;
    P0*=e0; P1*=e1; P2*=e2; P3*=e3;
  }
  size_t o=(((size_t)n*256+c0)*32+ch)*2;
  Pq[o]=P0; Pq[o+1]=q0; Pq[o+64]=P1; Pq[o+65]=q1;
  Pq[o+128]=P2; Pq[o+129]=q2; Pq[o+192]=P3; Pq[o+193]=q3;
}

__global__ __launch_bounds__(256) void k7mid(const float* __restrict__ Pq,float* __restrict__ h0)
{
  int nc=blockIdx.x*256+threadIdx.x;
  float h=0.f;
  for(int ch=0;ch<32;++ch){
    h0[(size_t)nc*32+ch]=h;
    h=h*Pq[((size_t)nc*32+ch)*2]+Pq[((size_t)nc*32+ch)*2+1];
  }
}

__global__ __launch_bounds__(256) void k7p2(unsigned short* __restrict__ uT,
  const unsigned short* __restrict__ dtT,const unsigned short* __restrict__ z2,
  const float* __restrict__ Bc,const float* __restrict__ Cc,
  const float* __restrict__ A_log,const float* __restrict__ Dp,
  const float* __restrict__ h0)
{
  int g=blockIdx.x*256+threadIdx.x;
  int cq=g&63, ch=(g>>6)&31, n=g>>11;
  int c0=cq*4;
  int d=n>>3, b=n&7, odd=d&1, s=(d>>1)*8+b;
  float A0=-__expf(A_log[c0]),A1=-__expf(A_log[c0+1]),A2=-__expf(A_log[c0+2]),A3=-__expf(A_log[c0+3]);
  float D0=Dp[c0],D1=Dp[c0+1],D2=Dp[c0+2],D3=Dp[c0+3];
  size_t tbase=((size_t)n*SEQL+ch*128)*256+c0;
  const unsigned short* zbase=z2+(size_t)s*SEQL*256+c0;
  const float* bp=Bc+(size_t)n*SEQL+ch*128;
  const float* cp=Cc+(size_t)n*SEQL+ch*128;
  size_t hb=((size_t)n*256+c0)*32+ch;
  float h0v=h0[hb],h1v=h0[hb+32],h2v=h0[hb+64],h3v=h0[hb+96];
  for(int t=0;t<128;++t){
    int tg=ch*128+t;
    int zr=odd? ((tg&~63)|((tg&63)^63)) : tg;
    uint2 uu=*(const uint2*)&uT[tbase+(size_t)t*256];
    uint2 dd=*(const uint2*)&dtT[tbase+(size_t)t*256];
    uint2 zz=*(const uint2*)&zbase[(size_t)zr*256];
    float u0,u1,u2,u3,d0,d1,d2,d3,z0,z1,z2v,z3;
    unp2(uu.x,u0,u1); unp2(uu.y,u2,u3);
    unp2(dd.x,d0,d1); unp2(dd.y,d2,d3);
    unp2(zz.x,z0,z1); unp2(zz.y,z2v,z3);
    float bv=bp[t], cv=cp[t];
    float e0=__expf(d0*A0),e1=__expf(d1*A1),e2=__expf(d2*A2),e3=__expf(d3*A3);
    h0v=h0v*e0+d0*bv*u0; h1v=h1v*e1+d1*bv*u1; h2v=h2v*e2+d2*bv*u2; h3v=h3v*e3+d3*bv*u3;
    float y0=(h0v*cv+u0*D0)*z0, y1=(h1v*cv+u1*D1)*z1;
    float y2=(h2v*cv+u2*D2)*z2v, y3=(h3v*cv+u3*D3)*z3;
    uint2 oo; oo.x=pk2(y0,y1); oo.y=pk2(y2,y3);
    *(uint2*)&uT[tbase+(size_t)t*256]=oo;
  }
}

// ---------------- k8am: out_proj 256->128 -> Y4 bf16 [n][t][128] (swapped) ----------------
__global__ __launch_bounds__(256) void k8am(const unsigned short* __restrict__ yT,
  const unsigned short* __restrict__ Woutb,unsigned short* __restrict__ Y4)
{
  MF_PRE();
  __shared__ __align__(16) short sA[64*72];
  __shared__ __align__(16) short sW[64*72];
  const int m0=blockIdx.x*64, n0=blockIdx.y*64, n=blockIdx.z;
  const unsigned short* ybase=yT+(size_t)n*SEQL*256;
  f32x4 acc[2][2]={};
  for(int k0=0;k0<256;k0+=64){
    STAGE_A_TOK_BF(ybase+(size_t)(m0+srow)*256+k0+sch*16);
    STAGE_W_BF(Woutb,256);
    __syncthreads();
    MF_STEP_SW();
    __syncthreads();
  }
  #pragma unroll
  for(int i=0;i<2;++i){ int oc0=n0+wn*32+i*16+fg*4;
    #pragma unroll
    for(int j=0;j<2;++j){ int tok=m0+wm*32+j*16+fr;
      uint2 pk;
      pk.x=pk2(acc[i][j][0],acc[i][j][1]);
      pk.y=pk2(acc[i][j][2],acc[i][j][3]);
      *(uint2*)&Y4[((size_t)n*SEQL+tok)*128+oc0]=pk; } }
}

// ---------------- k8bm: pi GEMM + gate + 4-dir sum -> ysum bf16 [b][t][128] (swapped) ----------------
__global__ __launch_bounds__(256) void k8bm(const unsigned short* __restrict__ Fp,
  const unsigned short* __restrict__ FpT,const unsigned short* __restrict__ Y4,
  const unsigned short* __restrict__ piwb,const float* __restrict__ pib,
  unsigned short* __restrict__ ysum)
{
  MF_PRE();
  __shared__ __align__(16) short sA[64*72];
  __shared__ __align__(16) short sW[64*72];
  const int m0=blockIdx.x*64, n0=blockIdx.y*64, b=blockIdx.z;
  f32x4 gs[2][2]={};
  for(int d=0;d<4;++d){
    const int n=d*8+b;
    const unsigned short* src=((d<2)?Fp:FpT)+(size_t)b*PIX*128;
    const unsigned short* Y4n=Y4+(size_t)n*SEQL*128;
    const int rev=(d&1)?63:0;
    f32x4 acc[2][2]={};
    for(int k0=0;k0<256;k0+=64){
      if(k0<128){
        int t=m0+srow; int tm=(t&~63)|((t&63)^rev);
        STAGE_A_TOK_BF(src+(size_t)tm*128+k0+sch*16);
      } else {
        STAGE_A_TOK_BF(Y4n+(size_t)(m0+srow)*128+(k0-128)+sch*16);
      }
      STAGE_W_BF(piwb,256);
      __syncthreads();
      MF_STEP_SW();
      __syncthreads();
    }
    #pragma unroll
    for(int i=0;i<2;++i){ int oc0=n0+wn*32+i*16+fg*4;
      float4 pb4=*(const float4*)&pib[oc0];
      #pragma unroll
      for(int j=0;j<2;++j){ int tok=m0+wm*32+j*16+fr;
        int tm=(tok&~63)|((tok&63)^rev);
        uint2 xv=*(const uint2*)&src[(size_t)tm*128+oc0];
        uint2 yv=*(const uint2*)&Y4n[(size_t)tok*128+oc0];
        float x0,x1v,x2v,x3v,y0,y1,y2,y3;
        unp2(xv.x,x0,x1v); unp2(xv.y,x2v,x3v);
        unp2(yv.x,y0,y1);  unp2(yv.y,y2,y3);
        float p0=sigm(acc[i][j][0]+pb4.x), p1=sigm(acc[i][j][1]+pb4.y);
        float p2=sigm(acc[i][j][2]+pb4.z), p3=sigm(acc[i][j][3]+pb4.w);
        gs[i][j][0]+=y0*p0+x0*(1.f-p0);
        gs[i][j][1]+=y1*p1+x1v*(1.f-p1);
        gs[i][j][2]+=y2*p2+x2v*(1.f-p2);
        gs[i][j][3]+=y3*p3+x3v*(1.f-p3);
      } }
  }
  #pragma unroll
  for(int i=0;i<2;++i){ int oc0=n0+wn*32+i*16+fg*4;
    #pragma unroll
    for(int j=0;j<2;++j){ int tok=m0+wm*32+j*16+fr;
      uint2 pk;
      pk.x=pk2(gs[i][j][0],gs[i][j][1]);
      pk.y=pk2(gs[i][j][2],gs[i][j][3]);
      *(uint2*)&ysum[((size_t)b*PIX+tok)*128+oc0]=pk; } }
}

// ---------------- k9m: final conv1x1 ((ysum+Fp) @ fw) -> out fp32 [b][c][t] ----------------
__global__ __launch_bounds__(256) void k9m(const unsigned short* __restrict__ ysum,
  const unsigned short* __restrict__ Fp,const unsigned short* __restrict__ fwb,
  float* __restrict__ out)
{
  MF_PRE();
  __shared__ __align__(16) short sA[64*72];
  __shared__ __align__(16) short sW[64*72];
  const int m0=blockIdx.x*64, n0=blockIdx.y*64, b=blockIdx.z;
  f32x4 acc[2][2]={};
  for(int k0=0;k0<128;k0+=64){
    { size_t off=((size_t)b*PIX+m0+srow)*128+k0+sch*16;
      STAGE_A_SUM_BF(ysum+off,Fp+off); }
    STAGE_W_BF(fwb,128);
    __syncthreads();
    MF_STEP();
    __syncthreads();
  }
  #pragma unroll
  for(int jn=0;jn<2;++jn){ int oc=n0+wn*32+jn*16+fr;
    #pragma unroll
    for(int i=0;i<2;++i){ int mb=m0+wm*32+i*16+fg*4;
      *(float4*)&out[((size_t)b*128+oc)*PIX+mb]=
        make_float4(acc[i][jn][0],acc[i][jn][1],acc[i][jn][2],acc[i][jn][3]); } }
}

extern "C" void kernel_launch(void* const* d_in,const int* in_sizes,int n_in,
  void* d_out,int out_size,void* d_ws,size_t ws_size,hipStream_t stream)
{
  (void)in_sizes; (void)n_in; (void)out_size; (void)ws_size;
  const float* FT1=(const float*)d_in[0];
  const float* FT2=(const float*)d_in[1];
  const float* gpw=(const float*)d_in[2];
  const float* g1g=(const float*)d_in[3];
  const float* g1b=(const float*)d_in[4];
  const float* g1m=(const float*)d_in[5];
  const float* g1v=(const float*)d_in[6];
  const float* gcw=(const float*)d_in[7];
  const float* g2g=(const float*)d_in[8];
  const float* g2b=(const float*)d_in[9];
  const float* g2m=(const float*)d_in[10];
  const float* g2v=(const float*)d_in[11];
  const float* sw1=(const float*)d_in[12];
  const float* sw2=(const float*)d_in[13];
  const float* prw=(const float*)d_in[14];
  const float* b3g=(const float*)d_in[15];
  const float* b3b=(const float*)d_in[16];
  const float* b3m=(const float*)d_in[17];
  const float* b3v=(const float*)d_in[18];
  const float* ipw=(const float*)d_in[19];
  const float* c1w=(const float*)d_in[20];
  const float* c1b=(const float*)d_in[21];
  const float* xpw=(const float*)d_in[22];
  const float* dtw=(const float*)d_in[23];
  const float* dtb=(const float*)d_in[24];
  const float* Alog=(const float*)d_in[25];
  const float* Dp=(const float*)d_in[26];
  const float* opw=(const float*)d_in[27];
  const float* piw=(const float*)d_in[28];
  const float* pib=(const float*)d_in[29];
  const float* fw=(const float*)d_in[30];

  char* w=(char*)d_ws;
  const size_t MB=1ull<<20;
  unsigned short* x1b =(unsigned short*)(w);            // 32MB bf16 [b][c][t]
  unsigned short* x2b =(unsigned short*)(w+32*MB);      // 32MB
  unsigned short* uT  =(unsigned short*)(w);            // 64MB [n=32][t][256] (after k5m)
  unsigned short* xs2 =(unsigned short*)(w+64*MB);      // 32MB [s=16][t][256]
  unsigned short* dtT =(unsigned short*)(w+64*MB);      // 64MB (after k6b; xs2 dead)
  unsigned short* Y4  =(unsigned short*)(w+64*MB);      // 32MB (after k7p2; dtT dead)
  unsigned short* z2  =(unsigned short*)(w+128*MB);     // 32MB [s=16][t][256]
  unsigned short* Fpb =(unsigned short*)(w+192*MB);     // 8MB  [b][t][128]
  unsigned short* FpTb=(unsigned short*)(w+200*MB);     // 8MB
  unsigned short* ysb =(unsigned short*)(w+208*MB);     // 8MB
  float* Bc =(float*)(w+216*MB);                        // 512KB
  float* Cc =(float*)(w+216*MB+512*1024);               // 512KB
  float* sr =(float*)(w+217*MB);                        // 32KB
  float* sse=(float*)(w+217*MB+32*1024);                // 32KB
  float* Pq =(float*)(w+218*MB);                        // 2MB
  float* h0 =(float*)(w+220*MB);                        // 1MB
  unsigned short* Wcb =(unsigned short*)(w+221*MB);     // 128KB
  unsigned short* gpwb=(unsigned short*)(w+222*MB);     // 256KB
  unsigned short* ipwb=(unsigned short*)(w+223*MB);     // 128KB
  unsigned short* opwb=(unsigned short*)(w+224*MB);     // 64KB
  unsigned short* piwb=(unsigned short*)(w+224*MB+64*1024); // 64KB
  unsigned short* fwb =(unsigned short*)(w+224*MB+128*1024);// 32KB
  unsigned short* Wsb =(unsigned short*)(w+225*MB);     // 2MB

  kWb<<<512,256,0,stream>>>(gpw,ipw,opw,piw,fw,gpwb,ipwb,opwb,piwb,fwb);
  kWc<<<256,256,0,stream>>>(dtw,xpw,Wcb);
  k1m<<<dim3(64,8,8),256,0,stream>>>(FT1,FT2,gpwb,g1g,g1b,g1m,g1v,x1b);
  k2<<<16384,256,0,stream>>>(x1b,gcw,g2g,g2b,g2m,g2v,x2b);
  k3<<<8192,256,0,stream>>>(x1b,x2b,sr);
  k4<<<8,256,0,stream>>>(sr,sw1,sw2,sse);
  kWse<<<4096,256,0,stream>>>(prw,sse,Wsb);
  k5m<<<dim3(64,2,8),256,0,stream>>>(x1b,x2b,Wsb,b3g,b3b,b3m,b3v,Fpb,FpTb);
  k6am<<<dim3(64,8,16),256,0,stream>>>(Fpb,FpTb,ipwb,xs2,z2);
  k6b<<<2048,256,0,stream>>>(xs2,c1w,c1b,uT);
  k6cm<<<dim3(64,4,32),256,0,stream>>>(uT,Wcb,dtb,dtT);
  k6bc<<<32768,256,0,stream>>>(uT,xpw,Bc,Cc);
  k7p1<<<256,256,0,stream>>>(uT,dtT,Bc,Alog,Pq);
  k7mid<<<32,256,0,stream>>>(Pq,h0);
  k7p2<<<256,256,0,stream>>>(uT,dtT,z2,Bc,Cc,Alog,Dp,h0);
  k8am<<<dim3(64,2,32),256,0,stream>>>(uT,opwb,Y4);
  k8bm<<<dim3(64,2,8),256,0,stream>>>(Fpb,FpTb,Y4,piwb,pib,ysb);
  k9m<<<dim3(64,2,8),256,0,stream>>>(ysb,Fpb,fwb,(float*)d_out);
}